// Round 6
// baseline (530.178 us; speedup 1.0000x reference)
//
#include <hip/hip_runtime.h>
#include <hip/hip_bf16.h>
#include <math.h>

#define B_ 4
#define S_ 2048
#define D_ 1024
#define M_ (B_*S_)   // 8192 rows total across batch
#define MBYTE (1024ull*1024ull)

typedef __attribute__((ext_vector_type(8))) _Float16 f16x8;  // 8 f16 = 4 VGPRs (MFMA A/B frag)
typedef __attribute__((ext_vector_type(4))) float f32x4;     // MFMA C/D frag
typedef __attribute__((ext_vector_type(8))) unsigned short us8;
typedef unsigned short us;

__device__ inline us f2h(float f) {
    union { _Float16 h; us u; } x;
    x.h = (_Float16)f;   // RTE
    return x.u;
}
__device__ inline float h2f(us u) {
    union { us u; _Float16 h; } x; x.u = u;
    return (float)x.h;
}

__device__ inline void gload16(const us* g, us* l) {
    __builtin_amdgcn_global_load_lds(
        (const __attribute__((address_space(1))) unsigned int*)g,
        (__attribute__((address_space(3))) unsigned int*)l, 16, 0, 0);
}

// ---------------------------------------------------------------------------
// Split cast: f32 -> hi fp16 (+ lo fp16 residual if DO_LO). 4 elems/thread.
// ---------------------------------------------------------------------------
template<int DO_LO>
__global__ __launch_bounds__(256)
void cast2_k(const float* __restrict__ in, us* __restrict__ hi, us* __restrict__ lo) {
    const size_t i = ((size_t)blockIdx.x * 256 + threadIdx.x) * 4;
    const float4 v = *(const float4*)&in[i];
    ushort4 h;
    h.x = f2h(v.x); h.y = f2h(v.y); h.z = f2h(v.z); h.w = f2h(v.w);
    *(ushort4*)&hi[i] = h;
    if (DO_LO) {
        ushort4 l;
        l.x = f2h(v.x - h2f(h.x)); l.y = f2h(v.y - h2f(h.y));
        l.z = f2h(v.z - h2f(h.z)); l.w = f2h(v.w - h2f(h.w));
        *(ushort4*)&lo[i] = l;
    }
}

// ---------------------------------------------------------------------------
// Weight transpose + split cast: W fp32 [K][N] -> Wt1(,Wt2) fp16 [N][K].
// ---------------------------------------------------------------------------
template<int DO_LO>
__global__ __launch_bounds__(256)
void wsplit_k(const float* __restrict__ W, us* __restrict__ Wt1, us* __restrict__ Wt2) {
    __shared__ float t[64][65];
    const int tid = threadIdx.x;
    const int k0 = blockIdx.x*64, n0 = blockIdx.y*64;
    #pragma unroll
    for (int i = 0; i < 4; ++i) {
        const int c = i*256 + tid;
        const int row = c >> 4, col = (c & 15) * 4;
        const float4 v = *(const float4*)&W[(size_t)(k0+row)*D_ + n0+col];
        t[row][col]=v.x; t[row][col+1]=v.y; t[row][col+2]=v.z; t[row][col+3]=v.w;
    }
    __syncthreads();
    #pragma unroll
    for (int i = 0; i < 4; ++i) {
        const int c = i*256 + tid;
        const int n = c >> 4, k = (c & 15) * 4;
        float f[4] = { t[k][n], t[k+1][n], t[k+2][n], t[k+3][n] };
        ushort4 h;
        h.x=f2h(f[0]); h.y=f2h(f[1]); h.z=f2h(f[2]); h.w=f2h(f[3]);
        *(ushort4*)&Wt1[(size_t)(n0+n)*D_ + k0+k] = h;
        if (DO_LO) {
            ushort4 l;
            l.x=f2h(f[0]-h2f(h.x)); l.y=f2h(f[1]-h2f(h.y));
            l.z=f2h(f[2]-h2f(h.z)); l.w=f2h(f[3]-h2f(h.w));
            *(ushort4*)&Wt2[(size_t)(n0+n)*D_ + k0+k] = l;
        }
    }
}

// ---------------------------------------------------------------------------
// Reduce 8 fp32 K-split partial slabs of W' and emit hi/lo split fp16.
// ---------------------------------------------------------------------------
__global__ __launch_bounds__(256)
void wreduce_k(const float* __restrict__ Wp, us* __restrict__ W1, us* __restrict__ W2) {
    const size_t i = ((size_t)blockIdx.x * 256 + threadIdx.x) * 4;
    float4 s = *(const float4*)&Wp[i];
    #pragma unroll
    for (int z = 1; z < 8; ++z) {
        const float4 v = *(const float4*)&Wp[(size_t)z*D_*D_ + i];
        s.x += v.x; s.y += v.y; s.z += v.z; s.w += v.w;
    }
    ushort4 h, l;
    h.x=f2h(s.x); h.y=f2h(s.y); h.z=f2h(s.z); h.w=f2h(s.w);
    l.x=f2h(s.x-h2f(h.x)); l.y=f2h(s.y-h2f(h.y));
    l.z=f2h(s.z-h2f(h.z)); l.w=f2h(s.w-h2f(h.w));
    *(ushort4*)&W1[i] = h;
    *(ushort4*)&W2[i] = l;
}

// ---------------------------------------------------------------------------
// b' = bk @ Wr + br. ROUND-3 LESSON: 4-block version was latency-bound.
// bpinit seeds bp=br; bprime does (4,16) e-chunked partials via atomicAdd.
// ---------------------------------------------------------------------------
__global__ __launch_bounds__(256)
void bpinit_k(const float* __restrict__ br, float* __restrict__ bp) {
    const int r = blockIdx.x * 256 + threadIdx.x;
    bp[r] = br[r];
}
__global__ __launch_bounds__(256)
void bprime_k(const float* __restrict__ bk, const float* __restrict__ Wr,
              float* __restrict__ bp) {
    const int r = blockIdx.x * 256 + threadIdx.x;
    const int e0 = blockIdx.y * 64;
    float a0 = 0.f, a1 = 0.f, a2 = 0.f, a3 = 0.f;
    for (int e = e0; e < e0 + 64; e += 4) {
        a0 += bk[e+0] * Wr[(size_t)(e+0)*D_ + r];
        a1 += bk[e+1] * Wr[(size_t)(e+1)*D_ + r];
        a2 += bk[e+2] * Wr[(size_t)(e+2)*D_ + r];
        a3 += bk[e+3] * Wr[(size_t)(e+3)*D_ + r];
    }
    atomicAdd(&bp[r], (a0 + a1) + (a2 + a3));
}

// ---------------------------------------------------------------------------
// fp16 MFMA GEMM: C[M][N] = A[M][K] @ Bt[N][K]^T, fp32 accumulate.
// 128x128 tile, 4 waves 2x2, global_load_lds width-16 staging, and
// ROUND-6: 2-phase double-buffered staging (T3 minimum recipe):
//   prologue STAGE(buf0); barrier;
//   loop: STAGE(buf^1, next) BEFORE compute(buf); ONE barrier per K-step.
// WHY (round-5 measurement): these dispatches are exposed-staging-latency
// bound -- time tracked staged bytes exactly (r4 512 MB/134us vs r5
// 832 MB/219us = 1.63x both), at only ~11% of L2 BW, grid-capped at
// 2 blocks/CU. Prefetch-into-other-buffer hides the load latency under
// ds_read+MFMA; the barrier's vmcnt(0) drain then finds loads landed.
// Plain: BK=64, 2 bufs -> 64 KB dbuf. SPLIT: BK=32, 4 bufs -> 64 KB dbuf
// (same accumulation order as the old BK=64/kk-loop form: bit-identical).
//
// ROUND-1 LESSON (do not redo): virtual-K restructure of the split GEMM
//   lowered MFMA-per-staged-byte 3x -> 127->264us.
// ROUND-3 LESSON: <256-block dispatches are latency-dead (0.6% occ);
//   K-split (KS) to >=512 blocks.
// ROUND-5 LESSON (do not redo): splitting the split-GEMM into plain passes
//   raises total staged bytes 1.63x -> time 1.63x. Staged bytes is the
//   currency; reduce exposure, not MFMA density.
//
// EPI: 0 = fp32 store (z-offset sC); 1 = f16(acc + colbias);
//      2 = f16(cos(acc + colbias)); 4 = f16(acc + ROW bias) [direct-V^T].
// Epilogue is LDS-staged so all global stores are 16B/lane coalesced.
// ---------------------------------------------------------------------------
template<int Nv, int Kv, int SPLIT, int EPI, int KS>
__global__ __launch_bounds__(256)
void gemm_bt_k(const us* __restrict__ A1, const us* __restrict__ A2,
               const us* __restrict__ B1, const us* __restrict__ B2,
               const float* __restrict__ bias, void* __restrict__ Cv,
               long sA, long sB, long sC) {
    constexpr int BK   = SPLIT ? 32 : 64;
    constexpr int NMAT = SPLIT ? 4 : 2;
    constexpr int BUFE = NMAT * 128 * BK;        // 16384 elems per buffer set
    __shared__ us smem[2 * BUFE];                // 64 KB double-buffered
    const int tid = threadIdx.x;
    const us* A1b = A1 + (size_t)blockIdx.z * sA;
    const us* A2b = SPLIT ? A2 + (size_t)blockIdx.z * sA : nullptr;
    const us* B1b = B1 + (size_t)blockIdx.z * sB;
    const us* B2b = SPLIT ? B2 + (size_t)blockIdx.z * sB : nullptr;
    const int m0 = blockIdx.x * 128, n0 = blockIdx.y * 128;   // m on x: XCD swizzle
    const int lane = tid & 63, w = tid >> 6;
    const int mw = (w >> 1) * 64, nw = (w & 1) * 64;
    const int lr = lane & 15, lq = lane >> 4;

    constexpr int SI = BK / 16;                  // stage i-iters per matrix
    const int srow = tid / (BK/8);               // staging row within i-chunk
    const int scol = (tid % (BK/8)) * 8;         // staging col (elems)

    f32x4 acc[4][4];
    #pragma unroll
    for (int i = 0; i < 4; ++i)
        #pragma unroll
        for (int j = 0; j < 4; ++j)
            acc[i][j] = (f32x4){0.f, 0.f, 0.f, 0.f};

    int kc0 = 0, kc1 = Kv;
    if (KS > 1) {
        const int kchunk = Kv / KS;
        kc0 = blockIdx.z * kchunk;
        kc1 = kc0 + kchunk;
    }

    auto STAGE = [&](int b, int kc) {
        us* dst = smem + b * BUFE;
        #pragma unroll
        for (int i = 0; i < SI; ++i) {
            const int r = srow + i * (128 / SI);
            const size_t off = (size_t)(i*256 + tid) * 8;   // = (row*BK+col) elems
            gload16(&A1b[(size_t)(m0 + r) * Kv + kc + scol], &dst[off]);
            gload16(&B1b[(size_t)(n0 + r) * Kv + kc + scol], &dst[128*BK + off]);
            if (SPLIT) {
                gload16(&A2b[(size_t)(m0 + r) * Kv + kc + scol], &dst[2*128*BK + off]);
                gload16(&B2b[(size_t)(n0 + r) * Kv + kc + scol], &dst[3*128*BK + off]);
            }
        }
    };

    auto COMPUTE = [&](int b) {
        const us* As_  = smem + b * BUFE;
        const us* Bs_  = As_ + 128*BK;
        const us* As2_ = As_ + 2*128*BK;
        const us* Bs2_ = As_ + 3*128*BK;
        #pragma unroll
        for (int kk = 0; kk < BK; kk += 32) {
            f16x8 a1[4], b1[4];
            #pragma unroll
            for (int i = 0; i < 4; ++i)
                a1[i] = *(const f16x8*)&As_[(mw + i*16 + lr) * BK + kk + lq*8];
            #pragma unroll
            for (int j = 0; j < 4; ++j)
                b1[j] = *(const f16x8*)&Bs_[(nw + j*16 + lr) * BK + kk + lq*8];
            if (SPLIT) {
                f16x8 a2[4], b2[4];
                #pragma unroll
                for (int i = 0; i < 4; ++i)
                    a2[i] = *(const f16x8*)&As2_[(mw + i*16 + lr) * BK + kk + lq*8];
                #pragma unroll
                for (int j = 0; j < 4; ++j)
                    b2[j] = *(const f16x8*)&Bs2_[(nw + j*16 + lr) * BK + kk + lq*8];
                #pragma unroll
                for (int i = 0; i < 4; ++i)
                    #pragma unroll
                    for (int j = 0; j < 4; ++j) {
                        acc[i][j] = __builtin_amdgcn_mfma_f32_16x16x32_f16(a2[i], b1[j], acc[i][j], 0, 0, 0);
                        acc[i][j] = __builtin_amdgcn_mfma_f32_16x16x32_f16(a1[i], b2[j], acc[i][j], 0, 0, 0);
                        acc[i][j] = __builtin_amdgcn_mfma_f32_16x16x32_f16(a1[i], b1[j], acc[i][j], 0, 0, 0);
                    }
            } else {
                #pragma unroll
                for (int i = 0; i < 4; ++i)
                    #pragma unroll
                    for (int j = 0; j < 4; ++j)
                        acc[i][j] = __builtin_amdgcn_mfma_f32_16x16x32_f16(a1[i], b1[j], acc[i][j], 0, 0, 0);
            }
        }
    };

    // prologue
    STAGE(0, kc0);
    __syncthreads();
    int cur = 0;
    for (int kc = kc0; kc < kc1; kc += BK) {
        if (kc + BK < kc1) STAGE(cur ^ 1, kc + BK);   // prefetch BEFORE compute
        COMPUTE(cur);
        __syncthreads();                              // one barrier per K-step
        cur ^= 1;
    }

    // ---------------- coalesced epilogue ----------------
    float* slab = (float*)smem + (size_t)w * 2048;   // 32x64 fp32 per-wave slab
    const int lrow0 = lane >> 3, cb = (lane & 7) * 8;
    #pragma unroll
    for (int p = 0; p < 2; ++p) {
        #pragma unroll
        for (int ii = 0; ii < 2; ++ii) {
            const int i = p*2 + ii;
            #pragma unroll
            for (int j = 0; j < 4; ++j)
                #pragma unroll
                for (int r = 0; r < 4; ++r)
                    slab[(ii*16 + lq*4 + r)*64 + j*16 + lr] = acc[i][j][r];
        }
        __syncthreads();
        #pragma unroll
        for (int t = 0; t < 4; ++t) {
            const int lrow = t*8 + lrow0;
            const int grow = m0 + mw + p*32 + lrow;
            const int gcol = n0 + nw + cb;
            const size_t idx = (size_t)grow * Nv + gcol;
            float v[8];
            #pragma unroll
            for (int u = 0; u < 8; ++u) v[u] = slab[lrow*64 + cb + u];
            if (EPI == 0) {
                float* Cf = (float*)Cv + (size_t)blockIdx.z * sC;
                float4 o0 = {v[0],v[1],v[2],v[3]}, o1 = {v[4],v[5],v[6],v[7]};
                *(float4*)&Cf[idx] = o0;
                *(float4*)&Cf[idx+4] = o1;
            } else if (EPI == 1 || EPI == 2) {
                us* Ch = (us*)Cv + (size_t)blockIdx.z * sC;
                us8 o;
                #pragma unroll
                for (int u = 0; u < 8; ++u) {
                    const float tv = v[u] + (bias ? bias[gcol + u] : 0.f);
                    o[u] = f2h(EPI == 2 ? cosf(tv) : tv);
                }
                *(us8*)&Ch[idx] = o;
            } else {                                  // EPI == 4: row bias
                us* Ch = (us*)Cv + (size_t)blockIdx.z * sC;
                const float rb = bias ? bias[grow] : 0.f;
                us8 o;
                #pragma unroll
                for (int u = 0; u < 8; ++u) o[u] = f2h(v[u] + rb);
                *(us8*)&Ch[idx] = o;
            }
        }
        __syncthreads();
    }
}

// ---------------------------------------------------------------------------
// Row softmax: S fp32 [S_] per row -> normalized P fp16. One block per row.
// ---------------------------------------------------------------------------
__global__ __launch_bounds__(256)
void softmax_k(const float* __restrict__ S, us* __restrict__ P) {
    __shared__ float red[8];
    const int tid = threadIdx.x;
    const int lane = tid & 63, w = tid >> 6;
    const float* row = S + (size_t)blockIdx.x * S_;

    const float4 v0 = *(const float4*)&row[tid*8];
    const float4 v1 = *(const float4*)&row[tid*8 + 4];
    float e[8] = {v0.x, v0.y, v0.z, v0.w, v1.x, v1.y, v1.z, v1.w};

    float mx = e[0];
    #pragma unroll
    for (int j = 1; j < 8; ++j) mx = fmaxf(mx, e[j]);
    #pragma unroll
    for (int off = 1; off < 64; off <<= 1) mx = fmaxf(mx, __shfl_xor(mx, off));
    if (lane == 0) red[w] = mx;
    __syncthreads();
    mx = fmaxf(fmaxf(red[0], red[1]), fmaxf(red[2], red[3]));

    float sum = 0.f;
    #pragma unroll
    for (int j = 0; j < 8; ++j) { e[j] = __expf(e[j] - mx); sum += e[j]; }
    #pragma unroll
    for (int off = 1; off < 64; off <<= 1) sum += __shfl_xor(sum, off);
    if (lane == 0) red[4 + w] = sum;
    __syncthreads();
    const float inv = 1.0f / (red[4] + red[5] + red[6] + red[7]);

    us8 o;
    #pragma unroll
    for (int j = 0; j < 8; ++j) o[j] = f2h(e[j] * inv);
    *(us8*)&P[(size_t)blockIdx.x * S_ + tid*8] = o;
}

// ---------------------------------------------------------------------------
extern "C" void kernel_launch(void* const* d_in, const int* in_sizes, int n_in,
                              void* d_out, int out_size, void* d_ws, size_t ws_size,
                              hipStream_t stream) {
    const float* x  = (const float*)d_in[0];
    const float* y  = (const float*)d_in[1];
    const float* Wq = (const float*)d_in[2];
    const float* bq = (const float*)d_in[3];
    const float* Wk = (const float*)d_in[4];
    const float* bk = (const float*)d_in[5];
    const float* Wv = (const float*)d_in[6];
    const float* bv = (const float*)d_in[7];
    const float* Wr = (const float*)d_in[8];
    const float* br = (const float*)d_in[9];
    float* out = (float*)d_out;

    // ALGEBRA: Kh = cos(y@W' + b'), W' = Wk@Wr (K-split x8 + reduce),
    // b' = bk@Wr + br.  Kh itself stays ONE split GEMM (round-5 lesson).
    //
    // Workspace choreography (96 MB) == round-4 (verified passing):
    //  [ 0,16) y1                         live: cast .. V^T gemm
    //  [16,32) y2 -> xh -> P(b0,b1)
    //  [32,48) {Wp lo half} -> Qb -> P(b2,b3)
    //  [48,64) {Wp hi half} -> Kh
    //  [64,96) Wkf1@64 Wkf2@66 Wr1@68 Wr2@70 WT1@72 WT2@74 bp@76
    //          -> Wq1@64 -> S2@64 (32 MB) -> Vt@64 (16 MB), Wv1@80
    //  Wp (8 fp32 slabs, 32 MB) occupies [32,64) only during the W' chain;
    //  dead before Qb and Kh are written.
    // Pair {0,1} scores run FIRST (P01 lands @16 after xh dies); pair {2,3}
    // second (P23 @32 after Qb dies) -> P contiguous 0..3 -> one z=4 PV.
    char* wsb = (char*)d_ws;
    us*    y1   = (us*)(wsb +  0*MBYTE);
    us*    y2   = (us*)(wsb + 16*MBYTE);
    us*    xh   = (us*)(wsb + 16*MBYTE);
    us*    Pb   = (us*)(wsb + 16*MBYTE);    // P batches 0..3 contiguous [16,48)
    float* Wp   = (float*)(wsb + 32*MBYTE); // 8 x 4MB fp32 K-split partials
    us*    Qb   = (us*)(wsb + 32*MBYTE);
    us*    P23  = (us*)(wsb + 32*MBYTE);
    us*    Kh   = (us*)(wsb + 48*MBYTE);
    us*    Wkf1 = (us*)(wsb + 64*MBYTE);
    us*    Wkf2 = (us*)(wsb + 66*MBYTE);
    us*    Wr1  = (us*)(wsb + 68*MBYTE);
    us*    Wr2  = (us*)(wsb + 70*MBYTE);
    us*    WT1  = (us*)(wsb + 72*MBYTE);
    us*    WT2  = (us*)(wsb + 74*MBYTE);
    float* bp   = (float*)(wsb + 76*MBYTE);
    us*    Wq1  = (us*)(wsb + 64*MBYTE);
    float* S2   = (float*)(wsb + 64*MBYTE); // 32 MB, reused per batch pair
    us*    Vt   = (us*)(wsb + 64*MBYTE);    // [b][d][s] 16 MB
    us*    Wv1  = (us*)(wsb + 80*MBYTE);

    const dim3 bb(256);
    const dim3 gcast(M_*D_/1024), gcastW(D_*D_/1024), gw(16,16);
    const dim3 gproj(M_/128, D_/128);            // m on x -> XCD A-panel sharing

    // --- W' = Wk@Wr (K-split x8 + reduce), b' = bk@Wr + br ---
    cast2_k<1><<<gcast, bb, 0, stream>>>(y, y1, y2);
    cast2_k<1><<<gcastW, bb, 0, stream>>>(Wk, Wkf1, Wkf2);   // [d][e] flat
    wsplit_k<1><<<gw, bb, 0, stream>>>(Wr, Wr1, Wr2);        // [r][e]
    bpinit_k<<<dim3(D_/256), bb, 0, stream>>>(br, bp);
    bprime_k<<<dim3(D_/256, 16), bb, 0, stream>>>(bk, Wr, bp);
    gemm_bt_k<D_, D_, 1, 0, 8><<<dim3(D_/128, D_/128, 8), bb, 0, stream>>>(
        Wr1, Wr2, Wkf1, Wkf2, nullptr, (void*)Wp, 0, 0, (long)D_*D_);
    wreduce_k<<<dim3(D_*D_/1024), bb, 0, stream>>>(Wp, WT1, WT2);

    // --- Kh = cos(y@W' + b'): one split GEMM (dbuf BK=32) ---
    gemm_bt_k<D_, D_, 1, 2, 1><<<gproj, bb, 0, stream>>>(
        y1, y2, WT1, WT2, bp, (void*)Kh, 0, 0, 0);

    // --- Q ---
    cast2_k<0><<<gcast, bb, 0, stream>>>(x, xh, nullptr);
    wsplit_k<0><<<gw, bb, 0, stream>>>(Wq, Wq1, nullptr);
    gemm_bt_k<D_, D_, 0, 1, 1><<<gproj, bb, 0, stream>>>(
        xh, nullptr, Wq1, nullptr, bq, (void*)Qb, 0, 0, 0);

    // --- attention scores + softmax, batch pairs (z=2 -> 512 blocks, 2/CU).
    //     Pair {0,1} first (see layout). ---
    gemm_bt_k<S_, D_, 0, 0, 1><<<dim3(S_/128, S_/128, 2), bb, 0, stream>>>(
        Qb, nullptr, Kh, nullptr, nullptr,
        (void*)S2, (long)S_*D_, (long)S_*D_, (long)S_*S_);
    softmax_k<<<dim3(2*S_), bb, 0, stream>>>(S2, Pb);
    gemm_bt_k<S_, D_, 0, 0, 1><<<dim3(S_/128, S_/128, 2), bb, 0, stream>>>(
        Qb + 2*(size_t)S_*D_, nullptr, Kh + 2*(size_t)S_*D_, nullptr, nullptr,
        (void*)S2, (long)S_*D_, (long)S_*D_, (long)S_*S_);
    softmax_k<<<dim3(2*S_), bb, 0, stream>>>(S2, P23);

    // --- V^T directly: Vt[b][d][s] = sum_e Wv^T[d][e]*y[b][s][e] + bv[d] ---
    wsplit_k<0><<<gw, bb, 0, stream>>>(Wv, Wv1, nullptr);
    gemm_bt_k<S_, D_, 0, 4, 1><<<dim3(D_/128, S_/128, B_), bb, 0, stream>>>(
        Wv1, nullptr, y1, nullptr, bv, (void*)Vt,
        0, (long)S_*D_, (long)D_*S_);

    // --- PV: single z=4 dispatch, P contiguous in batch order ---
    gemm_bt_k<D_, S_, 0, 0, 1><<<dim3(S_/128, D_/128, B_), bb, 0, stream>>>(
        Pb, nullptr, Vt, nullptr, nullptr, (void*)out,
        (long)S_*S_, (long)D_*S_, (long)S_*D_);
}

// Round 7
// 471.855 us; speedup vs baseline: 1.1236x; 1.1236x over previous
//
#include <hip/hip_runtime.h>
#include <hip/hip_bf16.h>
#include <math.h>

#define B_ 4
#define S_ 2048
#define D_ 1024
#define M_ (B_*S_)   // 8192 rows total across batch
#define MBYTE (1024ull*1024ull)

typedef __attribute__((ext_vector_type(8))) _Float16 f16x8;  // 8 f16 = 4 VGPRs (MFMA A/B frag)
typedef __attribute__((ext_vector_type(4))) float f32x4;     // MFMA C/D frag
typedef __attribute__((ext_vector_type(8))) unsigned short us8;
typedef unsigned short us;

__device__ inline us f2h(float f) {
    union { _Float16 h; us u; } x;
    x.h = (_Float16)f;   // RTE
    return x.u;
}
__device__ inline float h2f(us u) {
    union { us u; _Float16 h; } x; x.u = u;
    return (float)x.h;
}

__device__ inline void gload16(const us* g, us* l) {
    __builtin_amdgcn_global_load_lds(
        (const __attribute__((address_space(1))) unsigned int*)g,
        (__attribute__((address_space(3))) unsigned int*)l, 16, 0, 0);
}

// ---------------------------------------------------------------------------
// Split cast: f32 -> hi fp16 (+ lo fp16 residual if DO_LO). 4 elems/thread.
// ---------------------------------------------------------------------------
template<int DO_LO>
__global__ __launch_bounds__(256)
void cast2_k(const float* __restrict__ in, us* __restrict__ hi, us* __restrict__ lo) {
    const size_t i = ((size_t)blockIdx.x * 256 + threadIdx.x) * 4;
    const float4 v = *(const float4*)&in[i];
    ushort4 h;
    h.x = f2h(v.x); h.y = f2h(v.y); h.z = f2h(v.z); h.w = f2h(v.w);
    *(ushort4*)&hi[i] = h;
    if (DO_LO) {
        ushort4 l;
        l.x = f2h(v.x - h2f(h.x)); l.y = f2h(v.y - h2f(h.y));
        l.z = f2h(v.z - h2f(h.z)); l.w = f2h(v.w - h2f(h.w));
        *(ushort4*)&lo[i] = l;
    }
}

// ---------------------------------------------------------------------------
// Weight transpose + split cast: W fp32 [K][N] -> Wt1(,Wt2) fp16 [N][K].
// ---------------------------------------------------------------------------
template<int DO_LO>
__global__ __launch_bounds__(256)
void wsplit_k(const float* __restrict__ W, us* __restrict__ Wt1, us* __restrict__ Wt2) {
    __shared__ float t[64][65];
    const int tid = threadIdx.x;
    const int k0 = blockIdx.x*64, n0 = blockIdx.y*64;
    #pragma unroll
    for (int i = 0; i < 4; ++i) {
        const int c = i*256 + tid;
        const int row = c >> 4, col = (c & 15) * 4;
        const float4 v = *(const float4*)&W[(size_t)(k0+row)*D_ + n0+col];
        t[row][col]=v.x; t[row][col+1]=v.y; t[row][col+2]=v.z; t[row][col+3]=v.w;
    }
    __syncthreads();
    #pragma unroll
    for (int i = 0; i < 4; ++i) {
        const int c = i*256 + tid;
        const int n = c >> 4, k = (c & 15) * 4;
        float f[4] = { t[k][n], t[k+1][n], t[k+2][n], t[k+3][n] };
        ushort4 h;
        h.x=f2h(f[0]); h.y=f2h(f[1]); h.z=f2h(f[2]); h.w=f2h(f[3]);
        *(ushort4*)&Wt1[(size_t)(n0+n)*D_ + k0+k] = h;
        if (DO_LO) {
            ushort4 l;
            l.x=f2h(f[0]-h2f(h.x)); l.y=f2h(f[1]-h2f(h.y));
            l.z=f2h(f[2]-h2f(h.z)); l.w=f2h(f[3]-h2f(h.w));
            *(ushort4*)&Wt2[(size_t)(n0+n)*D_ + k0+k] = l;
        }
    }
}

// ---------------------------------------------------------------------------
// Reduce 8 fp32 K-split partial slabs of W' and emit hi/lo split fp16.
// ---------------------------------------------------------------------------
__global__ __launch_bounds__(256)
void wreduce_k(const float* __restrict__ Wp, us* __restrict__ W1, us* __restrict__ W2) {
    const size_t i = ((size_t)blockIdx.x * 256 + threadIdx.x) * 4;
    float4 s = *(const float4*)&Wp[i];
    #pragma unroll
    for (int z = 1; z < 8; ++z) {
        const float4 v = *(const float4*)&Wp[(size_t)z*D_*D_ + i];
        s.x += v.x; s.y += v.y; s.z += v.z; s.w += v.w;
    }
    ushort4 h, l;
    h.x=f2h(s.x); h.y=f2h(s.y); h.z=f2h(s.z); h.w=f2h(s.w);
    l.x=f2h(s.x-h2f(h.x)); l.y=f2h(s.y-h2f(h.y));
    l.z=f2h(s.z-h2f(h.z)); l.w=f2h(s.w-h2f(h.w));
    *(ushort4*)&W1[i] = h;
    *(ushort4*)&W2[i] = l;
}

// ---------------------------------------------------------------------------
// b' = bk @ Wr + br. ROUND-3 LESSON: 4-block version was latency-bound.
// bpinit seeds bp=br; bprime does (4,16) e-chunked partials via atomicAdd.
// ---------------------------------------------------------------------------
__global__ __launch_bounds__(256)
void bpinit_k(const float* __restrict__ br, float* __restrict__ bp) {
    const int r = blockIdx.x * 256 + threadIdx.x;
    bp[r] = br[r];
}
__global__ __launch_bounds__(256)
void bprime_k(const float* __restrict__ bk, const float* __restrict__ Wr,
              float* __restrict__ bp) {
    const int r = blockIdx.x * 256 + threadIdx.x;
    const int e0 = blockIdx.y * 64;
    float a0 = 0.f, a1 = 0.f, a2 = 0.f, a3 = 0.f;
    for (int e = e0; e < e0 + 64; e += 4) {
        a0 += bk[e+0] * Wr[(size_t)(e+0)*D_ + r];
        a1 += bk[e+1] * Wr[(size_t)(e+1)*D_ + r];
        a2 += bk[e+2] * Wr[(size_t)(e+2)*D_ + r];
        a3 += bk[e+3] * Wr[(size_t)(e+3)*D_ + r];
    }
    atomicAdd(&bp[r], (a0 + a1) + (a2 + a3));
}

// ---------------------------------------------------------------------------
// fp16 MFMA GEMM: C[M][N] = A[M][K] @ Bt[N][K]^T, fp32 accumulate.
// 128x128 tile, BK=64, 4 waves 2x2, global_load_lds width-16 staging.
// blockIdx.x = M-tile (XCD = blk%8 = m%8 -> A-panel L2 sharing on one XCD).
//
// SPLIT=1: round-4 exact form. 4 LDS buffers (64 KB), single-buffered,
//   2x __syncthreads per K-step, 3 MFMA per fragment quad. 134.5 us
//   measured for the 8192x1024x1024 Kh GEMM. DO NOT touch (see lessons).
// SPLIT=0: BK=64 double-buffer (2x32 KB) with COUNTED vmcnt across RAW
//   barriers (T3+T4): {STAGE(next)=8 loads; vmcnt(8); s_barrier;
//   COMPUTE(cur); s_barrier}. vmcnt(8) waits only the PREVIOUS step's 8
//   loads (which had a full compute phase to land) and leaves the new 8
//   in flight across both barriers.
//
// ROUND-1 LESSON: virtual-K restructure of the split GEMM lowered
//   MFMA-per-staged-byte 3x -> 127->264us. Staged bytes is the currency.
// ROUND-3 LESSON: <256-block dispatches are latency-dead; K-split (KS).
// ROUND-5 LESSON: splitting the split-GEMM into plain passes raised staged
//   bytes 1.63x -> time 1.63x.
// ROUND-6 LESSON: dbuf under __syncthreads is USELESS -- the implicit
//   vmcnt(0) drains the prefetch at the very next barrier (m99/m100).
//   And BK=32 split dbuf halved per-barrier MFMA while doubling exposed
//   windows: 134.5 -> 196us. The counted-vmcnt form below is the only
//   dbuf that can pay (m218: counted-vs-drain0 = +38-73%).
//
// EPI: 0 = fp32 store (z-offset sC); 1 = f16(acc + colbias);
//      2 = f16(cos(acc + colbias)); 4 = f16(acc + ROW bias) [direct-V^T].
// Epilogue is LDS-staged so all global stores are 16B/lane coalesced.
// ---------------------------------------------------------------------------
template<int Nv, int Kv, int SPLIT, int EPI, int KS>
__global__ __launch_bounds__(256)
void gemm_bt_k(const us* __restrict__ A1, const us* __restrict__ A2,
               const us* __restrict__ B1, const us* __restrict__ B2,
               const float* __restrict__ bias, void* __restrict__ Cv,
               long sA, long sB, long sC) {
    __shared__ us smem[4*128*64];                // 64 KB both modes
    const int tid = threadIdx.x;
    const us* A1b = A1 + (size_t)blockIdx.z * sA;
    const us* A2b = SPLIT ? A2 + (size_t)blockIdx.z * sA : nullptr;
    const us* B1b = B1 + (size_t)blockIdx.z * sB;
    const us* B2b = SPLIT ? B2 + (size_t)blockIdx.z * sB : nullptr;
    const int m0 = blockIdx.x * 128, n0 = blockIdx.y * 128;   // m on x: XCD swizzle
    const int lane = tid & 63, w = tid >> 6;
    const int mw = (w >> 1) * 64, nw = (w & 1) * 64;
    const int lr = lane & 15, lq = lane >> 4;

    const int crow = tid >> 3;          // staging row (0..31, +32/i)
    const int ccol = (tid & 7) * 8;     // staging col chunk (elems)

    f32x4 acc[4][4];
    #pragma unroll
    for (int i = 0; i < 4; ++i)
        #pragma unroll
        for (int j = 0; j < 4; ++j)
            acc[i][j] = (f32x4){0.f, 0.f, 0.f, 0.f};

    int kc0 = 0, kc1 = Kv;
    if (KS > 1) {
        const int kchunk = Kv / KS;
        kc0 = blockIdx.z * kchunk;
        kc1 = kc0 + kchunk;
    }

    if constexpr (SPLIT) {
        // ---------- round-4 exact split path (single-buffer, 2 barriers) ----
        us* As  = smem;
        us* As2 = smem + 128*64;
        us* Bs  = smem + 2*128*64;
        us* Bs2 = smem + 3*128*64;
        for (int kc = kc0; kc < kc1; kc += 64) {
            #pragma unroll
            for (int i = 0; i < 4; ++i) {
                const int r = crow + i * 32;
                const size_t off = (size_t)(i*256 + tid) * 8;
                gload16(&A1b[(size_t)(m0 + r) * Kv + kc + ccol], &As[off]);
                gload16(&B1b[(size_t)(n0 + r) * Kv + kc + ccol], &Bs[off]);
                gload16(&A2b[(size_t)(m0 + r) * Kv + kc + ccol], &As2[off]);
                gload16(&B2b[(size_t)(n0 + r) * Kv + kc + ccol], &Bs2[off]);
            }
            __syncthreads();
            #pragma unroll
            for (int kk = 0; kk < 64; kk += 32) {
                f16x8 a1[4], b1[4], a2[4], b2[4];
                #pragma unroll
                for (int i = 0; i < 4; ++i) {
                    a1[i] = *(const f16x8*)&As [(mw + i*16 + lr) * 64 + kk + lq*8];
                    a2[i] = *(const f16x8*)&As2[(mw + i*16 + lr) * 64 + kk + lq*8];
                }
                #pragma unroll
                for (int j = 0; j < 4; ++j) {
                    b1[j] = *(const f16x8*)&Bs [(nw + j*16 + lr) * 64 + kk + lq*8];
                    b2[j] = *(const f16x8*)&Bs2[(nw + j*16 + lr) * 64 + kk + lq*8];
                }
                #pragma unroll
                for (int i = 0; i < 4; ++i)
                    #pragma unroll
                    for (int j = 0; j < 4; ++j) {
                        acc[i][j] = __builtin_amdgcn_mfma_f32_16x16x32_f16(a2[i], b1[j], acc[i][j], 0, 0, 0);
                        acc[i][j] = __builtin_amdgcn_mfma_f32_16x16x32_f16(a1[i], b2[j], acc[i][j], 0, 0, 0);
                        acc[i][j] = __builtin_amdgcn_mfma_f32_16x16x32_f16(a1[i], b1[j], acc[i][j], 0, 0, 0);
                    }
            }
            __syncthreads();
        }
    } else {
        // ---------- plain path: dbuf + counted vmcnt across raw barriers ----
        constexpr int BUFE = 2*128*64;           // A+B buffer set (32 KB)
        auto STAGE = [&](int b, int kc) {        // exactly 8 loads per thread
            us* dst = smem + b * BUFE;
            #pragma unroll
            for (int i = 0; i < 4; ++i) {
                const int r = crow + i * 32;
                const size_t off = (size_t)(i*256 + tid) * 8;
                gload16(&A1b[(size_t)(m0 + r) * Kv + kc + ccol], &dst[off]);
                gload16(&B1b[(size_t)(n0 + r) * Kv + kc + ccol], &dst[128*64 + off]);
            }
        };
        STAGE(0, kc0);
        int cur = 0;
        for (int kc = kc0; kc < kc1; kc += 64) {
            const bool pf = (kc + 64 < kc1);
            if (pf) {
                STAGE(cur ^ 1, kc + 64);
                asm volatile("s_waitcnt vmcnt(8)" ::: "memory");
            } else {
                asm volatile("s_waitcnt vmcnt(0)" ::: "memory");
            }
            __builtin_amdgcn_s_barrier();        // buf[cur] staged for ALL waves
            const us* As_ = smem + cur * BUFE;
            const us* Bs_ = As_ + 128*64;
            #pragma unroll
            for (int kk = 0; kk < 64; kk += 32) {
                f16x8 a1[4], b1[4];
                #pragma unroll
                for (int i = 0; i < 4; ++i)
                    a1[i] = *(const f16x8*)&As_[(mw + i*16 + lr) * 64 + kk + lq*8];
                #pragma unroll
                for (int j = 0; j < 4; ++j)
                    b1[j] = *(const f16x8*)&Bs_[(nw + j*16 + lr) * 64 + kk + lq*8];
                #pragma unroll
                for (int i = 0; i < 4; ++i)
                    #pragma unroll
                    for (int j = 0; j < 4; ++j)
                        acc[i][j] = __builtin_amdgcn_mfma_f32_16x16x32_f16(a1[i], b1[j], acc[i][j], 0, 0, 0);
            }
            __builtin_amdgcn_s_barrier();        // buf[cur] free to overwrite
            cur ^= 1;
        }
    }

    // ---------------- coalesced epilogue ----------------
    float* slab = (float*)smem + (size_t)w * 2048;   // 32x64 fp32 per-wave slab
    const int lrow0 = lane >> 3, cb = (lane & 7) * 8;
    #pragma unroll
    for (int p = 0; p < 2; ++p) {
        #pragma unroll
        for (int ii = 0; ii < 2; ++ii) {
            const int i = p*2 + ii;
            #pragma unroll
            for (int j = 0; j < 4; ++j)
                #pragma unroll
                for (int r = 0; r < 4; ++r)
                    slab[(ii*16 + lq*4 + r)*64 + j*16 + lr] = acc[i][j][r];
        }
        __syncthreads();
        #pragma unroll
        for (int t = 0; t < 4; ++t) {
            const int lrow = t*8 + lrow0;
            const int grow = m0 + mw + p*32 + lrow;
            const int gcol = n0 + nw + cb;
            const size_t idx = (size_t)grow * Nv + gcol;
            float v[8];
            #pragma unroll
            for (int u = 0; u < 8; ++u) v[u] = slab[lrow*64 + cb + u];
            if (EPI == 0) {
                float* Cf = (float*)Cv + (size_t)blockIdx.z * sC;
                float4 o0 = {v[0],v[1],v[2],v[3]}, o1 = {v[4],v[5],v[6],v[7]};
                *(float4*)&Cf[idx] = o0;
                *(float4*)&Cf[idx+4] = o1;
            } else if (EPI == 1 || EPI == 2) {
                us* Ch = (us*)Cv + (size_t)blockIdx.z * sC;
                us8 o;
                #pragma unroll
                for (int u = 0; u < 8; ++u) {
                    const float tv = v[u] + (bias ? bias[gcol + u] : 0.f);
                    o[u] = f2h(EPI == 2 ? cosf(tv) : tv);
                }
                *(us8*)&Ch[idx] = o;
            } else {                                  // EPI == 4: row bias
                us* Ch = (us*)Cv + (size_t)blockIdx.z * sC;
                const float rb = bias ? bias[grow] : 0.f;
                us8 o;
                #pragma unroll
                for (int u = 0; u < 8; ++u) o[u] = f2h(v[u] + rb);
                *(us8*)&Ch[idx] = o;
            }
        }
        __syncthreads();
    }
}

// ---------------------------------------------------------------------------
// Row softmax: S fp32 [S_] per row -> normalized P fp16. One block per row.
// ---------------------------------------------------------------------------
__global__ __launch_bounds__(256)
void softmax_k(const float* __restrict__ S, us* __restrict__ P) {
    __shared__ float red[8];
    const int tid = threadIdx.x;
    const int lane = tid & 63, w = tid >> 6;
    const float* row = S + (size_t)blockIdx.x * S_;

    const float4 v0 = *(const float4*)&row[tid*8];
    const float4 v1 = *(const float4*)&row[tid*8 + 4];
    float e[8] = {v0.x, v0.y, v0.z, v0.w, v1.x, v1.y, v1.z, v1.w};

    float mx = e[0];
    #pragma unroll
    for (int j = 1; j < 8; ++j) mx = fmaxf(mx, e[j]);
    #pragma unroll
    for (int off = 1; off < 64; off <<= 1) mx = fmaxf(mx, __shfl_xor(mx, off));
    if (lane == 0) red[w] = mx;
    __syncthreads();
    mx = fmaxf(fmaxf(red[0], red[1]), fmaxf(red[2], red[3]));

    float sum = 0.f;
    #pragma unroll
    for (int j = 0; j < 8; ++j) { e[j] = __expf(e[j] - mx); sum += e[j]; }
    #pragma unroll
    for (int off = 1; off < 64; off <<= 1) sum += __shfl_xor(sum, off);
    if (lane == 0) red[4 + w] = sum;
    __syncthreads();
    const float inv = 1.0f / (red[4] + red[5] + red[6] + red[7]);

    us8 o;
    #pragma unroll
    for (int j = 0; j < 8; ++j) o[j] = f2h(e[j] * inv);
    *(us8*)&P[(size_t)blockIdx.x * S_ + tid*8] = o;
}

// ---------------------------------------------------------------------------
extern "C" void kernel_launch(void* const* d_in, const int* in_sizes, int n_in,
                              void* d_out, int out_size, void* d_ws, size_t ws_size,
                              hipStream_t stream) {
    const float* x  = (const float*)d_in[0];
    const float* y  = (const float*)d_in[1];
    const float* Wq = (const float*)d_in[2];
    const float* bq = (const float*)d_in[3];
    const float* Wk = (const float*)d_in[4];
    const float* bk = (const float*)d_in[5];
    const float* Wv = (const float*)d_in[6];
    const float* bv = (const float*)d_in[7];
    const float* Wr = (const float*)d_in[8];
    const float* br = (const float*)d_in[9];
    float* out = (float*)d_out;

    // ALGEBRA: Kh = cos(y@W' + b'), W' = Wk@Wr (K-split x8 + reduce),
    // b' = bk@Wr + br.  Kh itself stays ONE split GEMM (round-5 lesson).
    //
    // Workspace choreography (96 MB) == round-4 (verified passing):
    //  [ 0,16) y1                         live: cast .. V^T gemm
    //  [16,32) y2 -> xh -> P(b0,b1)
    //  [32,48) {Wp lo half} -> Qb -> P(b2,b3)
    //  [48,64) {Wp hi half} -> Kh
    //  [64,96) Wkf1@64 Wkf2@66 Wr1@68 Wr2@70 WT1@72 WT2@74 bp@76
    //          -> Wq1@64 -> S2@64 (32 MB) -> Vt@64 (16 MB), Wv1@80
    //  Wp (8 fp32 slabs, 32 MB) occupies [32,64) only during the W' chain;
    //  dead before Qb and Kh are written.
    // Pair {0,1} scores run FIRST (P01 lands @16 after xh dies); pair {2,3}
    // second (P23 @32 after Qb dies) -> P contiguous 0..3 -> one z=4 PV.
    char* wsb = (char*)d_ws;
    us*    y1   = (us*)(wsb +  0*MBYTE);
    us*    y2   = (us*)(wsb + 16*MBYTE);
    us*    xh   = (us*)(wsb + 16*MBYTE);
    us*    Pb   = (us*)(wsb + 16*MBYTE);    // P batches 0..3 contiguous [16,48)
    float* Wp   = (float*)(wsb + 32*MBYTE); // 8 x 4MB fp32 K-split partials
    us*    Qb   = (us*)(wsb + 32*MBYTE);
    us*    P23  = (us*)(wsb + 32*MBYTE);
    us*    Kh   = (us*)(wsb + 48*MBYTE);
    us*    Wkf1 = (us*)(wsb + 64*MBYTE);
    us*    Wkf2 = (us*)(wsb + 66*MBYTE);
    us*    Wr1  = (us*)(wsb + 68*MBYTE);
    us*    Wr2  = (us*)(wsb + 70*MBYTE);
    us*    WT1  = (us*)(wsb + 72*MBYTE);
    us*    WT2  = (us*)(wsb + 74*MBYTE);
    float* bp   = (float*)(wsb + 76*MBYTE);
    us*    Wq1  = (us*)(wsb + 64*MBYTE);
    float* S2   = (float*)(wsb + 64*MBYTE); // 32 MB, reused per batch pair
    us*    Vt   = (us*)(wsb + 64*MBYTE);    // [b][d][s] 16 MB
    us*    Wv1  = (us*)(wsb + 80*MBYTE);

    const dim3 bb(256);
    const dim3 gcast(M_*D_/1024), gcastW(D_*D_/1024), gw(16,16);
    const dim3 gproj(M_/128, D_/128);            // m on x -> XCD A-panel sharing

    // --- W' = Wk@Wr (K-split x8 + reduce), b' = bk@Wr + br ---
    cast2_k<1><<<gcast, bb, 0, stream>>>(y, y1, y2);
    cast2_k<1><<<gcastW, bb, 0, stream>>>(Wk, Wkf1, Wkf2);   // [d][e] flat
    wsplit_k<1><<<gw, bb, 0, stream>>>(Wr, Wr1, Wr2);        // [r][e]
    bpinit_k<<<dim3(D_/256), bb, 0, stream>>>(br, bp);
    bprime_k<<<dim3(D_/256, 16), bb, 0, stream>>>(bk, Wr, bp);
    gemm_bt_k<D_, D_, 1, 0, 8><<<dim3(D_/128, D_/128, 8), bb, 0, stream>>>(
        Wr1, Wr2, Wkf1, Wkf2, nullptr, (void*)Wp, 0, 0, (long)D_*D_);
    wreduce_k<<<dim3(D_*D_/1024), bb, 0, stream>>>(Wp, WT1, WT2);

    // --- Kh = cos(y@W' + b'): one split GEMM (round-4 form) ---
    gemm_bt_k<D_, D_, 1, 2, 1><<<gproj, bb, 0, stream>>>(
        y1, y2, WT1, WT2, bp, (void*)Kh, 0, 0, 0);

    // --- Q ---
    cast2_k<0><<<gcast, bb, 0, stream>>>(x, xh, nullptr);
    wsplit_k<0><<<gw, bb, 0, stream>>>(Wq, Wq1, nullptr);
    gemm_bt_k<D_, D_, 0, 1, 1><<<gproj, bb, 0, stream>>>(
        xh, nullptr, Wq1, nullptr, bq, (void*)Qb, 0, 0, 0);

    // --- attention scores + softmax, batch pairs (z=2 -> 512 blocks, 2/CU).
    //     Pair {0,1} first (see layout). ---
    gemm_bt_k<S_, D_, 0, 0, 1><<<dim3(S_/128, S_/128, 2), bb, 0, stream>>>(
        Qb, nullptr, Kh, nullptr, nullptr,
        (void*)S2, (long)S_*D_, (long)S_*D_, (long)S_*S_);
    softmax_k<<<dim3(2*S_), bb, 0, stream>>>(S2, Pb);
    gemm_bt_k<S_, D_, 0, 0, 1><<<dim3(S_/128, S_/128, 2), bb, 0, stream>>>(
        Qb + 2*(size_t)S_*D_, nullptr, Kh + 2*(size_t)S_*D_, nullptr, nullptr,
        (void*)S2, (long)S_*D_, (long)S_*D_, (long)S_*S_);
    softmax_k<<<dim3(2*S_), bb, 0, stream>>>(S2, P23);

    // --- V^T directly: Vt[b][d][s] = sum_e Wv^T[d][e]*y[b][s][e] + bv[d] ---
    wsplit_k<0><<<gw, bb, 0, stream>>>(Wv, Wv1, nullptr);
    gemm_bt_k<S_, D_, 0, 4, 1><<<dim3(D_/128, S_/128, B_), bb, 0, stream>>>(
        Wv1, nullptr, y1, nullptr, bv, (void*)Vt,
        0, (long)S_*D_, (long)D_*S_);

    // --- PV: single z=4 dispatch, P contiguous in batch order ---
    gemm_bt_k<D_, S_, 0, 0, 1><<<dim3(S_/128, D_/128, B_), bb, 0, stream>>>(
        Pb, nullptr, Vt, nullptr, nullptr, (void*)out,
        (long)S_*S_, (long)D_*S_, (long)S_*D_);
}

// Round 8
// 425.156 us; speedup vs baseline: 1.2470x; 1.1098x over previous
//
#include <hip/hip_runtime.h>
#include <hip/hip_bf16.h>
#include <math.h>

#define B_ 4
#define S_ 2048
#define D_ 1024
#define M_ (B_*S_)   // 8192 rows total across batch
#define MBYTE (1024ull*1024ull)

typedef __attribute__((ext_vector_type(8))) _Float16 f16x8;  // 8 f16 = 4 VGPRs (MFMA A/B frag)
typedef __attribute__((ext_vector_type(4))) float f32x4;     // MFMA C/D frag
typedef __attribute__((ext_vector_type(8))) unsigned short us8;
typedef unsigned short us;

__device__ inline us f2h(float f) {
    union { _Float16 h; us u; } x;
    x.h = (_Float16)f;   // RTE
    return x.u;
}
__device__ inline float h2f(us u) {
    union { us u; _Float16 h; } x; x.u = u;
    return (float)x.h;
}

__device__ inline void gload16(const us* g, us* l) {
    __builtin_amdgcn_global_load_lds(
        (const __attribute__((address_space(1))) unsigned int*)g,
        (__attribute__((address_space(3))) unsigned int*)l, 16, 0, 0);
}

// ---------------------------------------------------------------------------
// Split cast: f32 -> hi fp16 (+ lo fp16 residual if DO_LO). 4 elems/thread.
// ---------------------------------------------------------------------------
template<int DO_LO>
__global__ __launch_bounds__(256)
void cast2_k(const float* __restrict__ in, us* __restrict__ hi, us* __restrict__ lo) {
    const size_t i = ((size_t)blockIdx.x * 256 + threadIdx.x) * 4;
    const float4 v = *(const float4*)&in[i];
    ushort4 h;
    h.x = f2h(v.x); h.y = f2h(v.y); h.z = f2h(v.z); h.w = f2h(v.w);
    *(ushort4*)&hi[i] = h;
    if (DO_LO) {
        ushort4 l;
        l.x = f2h(v.x - h2f(h.x)); l.y = f2h(v.y - h2f(h.y));
        l.z = f2h(v.z - h2f(h.z)); l.w = f2h(v.w - h2f(h.w));
        *(ushort4*)&lo[i] = l;
    }
}

// ---------------------------------------------------------------------------
// Weight transpose + split cast: W fp32 [K][N] -> Wt1(,Wt2) fp16 [N][K].
// ---------------------------------------------------------------------------
template<int DO_LO>
__global__ __launch_bounds__(256)
void wsplit_k(const float* __restrict__ W, us* __restrict__ Wt1, us* __restrict__ Wt2) {
    __shared__ float t[64][65];
    const int tid = threadIdx.x;
    const int k0 = blockIdx.x*64, n0 = blockIdx.y*64;
    #pragma unroll
    for (int i = 0; i < 4; ++i) {
        const int c = i*256 + tid;
        const int row = c >> 4, col = (c & 15) * 4;
        const float4 v = *(const float4*)&W[(size_t)(k0+row)*D_ + n0+col];
        t[row][col]=v.x; t[row][col+1]=v.y; t[row][col+2]=v.z; t[row][col+3]=v.w;
    }
    __syncthreads();
    #pragma unroll
    for (int i = 0; i < 4; ++i) {
        const int c = i*256 + tid;
        const int n = c >> 4, k = (c & 15) * 4;
        float f[4] = { t[k][n], t[k+1][n], t[k+2][n], t[k+3][n] };
        ushort4 h;
        h.x=f2h(f[0]); h.y=f2h(f[1]); h.z=f2h(f[2]); h.w=f2h(f[3]);
        *(ushort4*)&Wt1[(size_t)(n0+n)*D_ + k0+k] = h;
        if (DO_LO) {
            ushort4 l;
            l.x=f2h(f[0]-h2f(h.x)); l.y=f2h(f[1]-h2f(h.y));
            l.z=f2h(f[2]-h2f(h.z)); l.w=f2h(f[3]-h2f(h.w));
            *(ushort4*)&Wt2[(size_t)(n0+n)*D_ + k0+k] = l;
        }
    }
}

// ---------------------------------------------------------------------------
// Reduce 8 fp32 K-split partial slabs of W' and emit hi/lo split fp16.
// ---------------------------------------------------------------------------
__global__ __launch_bounds__(256)
void wreduce_k(const float* __restrict__ Wp, us* __restrict__ W1, us* __restrict__ W2) {
    const size_t i = ((size_t)blockIdx.x * 256 + threadIdx.x) * 4;
    float4 s = *(const float4*)&Wp[i];
    #pragma unroll
    for (int z = 1; z < 8; ++z) {
        const float4 v = *(const float4*)&Wp[(size_t)z*D_*D_ + i];
        s.x += v.x; s.y += v.y; s.z += v.z; s.w += v.w;
    }
    ushort4 h, l;
    h.x=f2h(s.x); h.y=f2h(s.y); h.z=f2h(s.z); h.w=f2h(s.w);
    l.x=f2h(s.x-h2f(h.x)); l.y=f2h(s.y-h2f(h.y));
    l.z=f2h(s.z-h2f(h.z)); l.w=f2h(s.w-h2f(h.w));
    *(ushort4*)&W1[i] = h;
    *(ushort4*)&W2[i] = l;
}

// ---------------------------------------------------------------------------
// b' = bk @ Wr + br. ROUND-3 LESSON: 4-block version was latency-bound.
// bpinit seeds bp=br; bprime does (4,16) e-chunked partials via atomicAdd.
// ---------------------------------------------------------------------------
__global__ __launch_bounds__(256)
void bpinit_k(const float* __restrict__ br, float* __restrict__ bp) {
    const int r = blockIdx.x * 256 + threadIdx.x;
    bp[r] = br[r];
}
__global__ __launch_bounds__(256)
void bprime_k(const float* __restrict__ bk, const float* __restrict__ Wr,
              float* __restrict__ bp) {
    const int r = blockIdx.x * 256 + threadIdx.x;
    const int e0 = blockIdx.y * 64;
    float a0 = 0.f, a1 = 0.f, a2 = 0.f, a3 = 0.f;
    for (int e = e0; e < e0 + 64; e += 4) {
        a0 += bk[e+0] * Wr[(size_t)(e+0)*D_ + r];
        a1 += bk[e+1] * Wr[(size_t)(e+1)*D_ + r];
        a2 += bk[e+2] * Wr[(size_t)(e+2)*D_ + r];
        a3 += bk[e+3] * Wr[(size_t)(e+3)*D_ + r];
    }
    atomicAdd(&bp[r], (a0 + a1) + (a2 + a3));
}

// ---------------------------------------------------------------------------
// fp16 MFMA GEMM: C[M][N] = A[M][K] @ Bt[N][K]^T, fp32 accumulate.
// 128x128 tile, 4 waves 2x2, global_load_lds width-16 staging.
// blockIdx.x = M-tile (XCD = blk%8 = m%8 -> A-panel L2 sharing on one XCD).
//
// BOTH paths now use T3+T4: double-buffer with COUNTED vmcnt across RAW
// barriers: {STAGE(next)=8 loads; vmcnt(8); s_barrier; COMPUTE(cur);
// s_barrier}. vmcnt(8) waits only the PREVIOUS step's 8 loads (which had
// a full compute phase + barrier to land) and leaves the new 8 in flight
// across both barriers.
//   SPLIT=0: BK=64, 2 buffer-sets x 32 KB. (round-7: part of 489->472)
//   SPLIT=1: BK=32, 4 matrices x 8 KB x 2 sets = 64 KB. Same k-chunk order
//     and same 3-MFMA inner order as the round-4 BK=64 form ->
//     bit-identical accumulation. (round-8 change)
//
// ROUND-1 LESSON: virtual-K restructure of the split GEMM lowered
//   MFMA-per-staged-byte 3x -> 127->264us. Staged bytes is the currency.
// ROUND-3 LESSON: <256-block dispatches are latency-dead; K-split (KS).
// ROUND-5 LESSON: splitting the split-GEMM into plain passes raised staged
//   bytes 1.63x -> time 1.63x.
// ROUND-6 LESSON: dbuf under __syncthreads is USELESS (implicit vmcnt(0)
//   drains the prefetch): BK=32 split drain0-dbuf = 134.5 -> 196us. Only
//   the counted-vmcnt form pays (m218: counted-vs-drain0 = +38-73%),
//   confirmed on the plain path in round 7.
//
// EPI: 0 = fp32 store (z-offset sC); 1 = f16(acc + colbias);
//      2 = f16(cos(acc + colbias)); 4 = f16(acc + ROW bias) [direct-V^T].
// Epilogue is LDS-staged so all global stores are 16B/lane coalesced.
// ---------------------------------------------------------------------------
template<int Nv, int Kv, int SPLIT, int EPI, int KS>
__global__ __launch_bounds__(256)
void gemm_bt_k(const us* __restrict__ A1, const us* __restrict__ A2,
               const us* __restrict__ B1, const us* __restrict__ B2,
               const float* __restrict__ bias, void* __restrict__ Cv,
               long sA, long sB, long sC) {
    __shared__ us smem[4*128*64];                // 64 KB both modes
    const int tid = threadIdx.x;
    const us* A1b = A1 + (size_t)blockIdx.z * sA;
    const us* A2b = SPLIT ? A2 + (size_t)blockIdx.z * sA : nullptr;
    const us* B1b = B1 + (size_t)blockIdx.z * sB;
    const us* B2b = SPLIT ? B2 + (size_t)blockIdx.z * sB : nullptr;
    const int m0 = blockIdx.x * 128, n0 = blockIdx.y * 128;   // m on x: XCD swizzle
    const int lane = tid & 63, w = tid >> 6;
    const int mw = (w >> 1) * 64, nw = (w & 1) * 64;
    const int lr = lane & 15, lq = lane >> 4;

    const int crow = tid >> 3;          // BK=64 staging row (0..31, +32/i)
    const int ccol = (tid & 7) * 8;     // BK=64 staging col chunk (elems)

    f32x4 acc[4][4];
    #pragma unroll
    for (int i = 0; i < 4; ++i)
        #pragma unroll
        for (int j = 0; j < 4; ++j)
            acc[i][j] = (f32x4){0.f, 0.f, 0.f, 0.f};

    int kc0 = 0, kc1 = Kv;
    if (KS > 1) {
        const int kchunk = Kv / KS;
        kc0 = blockIdx.z * kchunk;
        kc1 = kc0 + kchunk;
    }

    if constexpr (SPLIT) {
        // ---- split path: BK=32 dbuf + counted vmcnt (round-8) ----
        constexpr int BKS  = 32;
        constexpr int MATE = 128 * BKS;          // elems per matrix (8 KB)
        constexpr int BUFE = 4 * MATE;           // buffer set (32 KB)
        const int r0 = tid >> 2;                 // staging row (0..63, +64/i)
        const int c0 = (tid & 3) * 8;            // staging col (elems)
        auto STAGE = [&](int b, int kc) {        // exactly 8 loads per thread
            us* dst = smem + b * BUFE;
            #pragma unroll
            for (int i = 0; i < 2; ++i) {
                const int r = r0 + i * 64;
                const size_t off = (size_t)(i*256 + tid) * 8;   // row*BKS+col
                gload16(&A1b[(size_t)(m0 + r) * Kv + kc + c0], &dst[off]);
                gload16(&B1b[(size_t)(n0 + r) * Kv + kc + c0], &dst[MATE + off]);
                gload16(&A2b[(size_t)(m0 + r) * Kv + kc + c0], &dst[2*MATE + off]);
                gload16(&B2b[(size_t)(n0 + r) * Kv + kc + c0], &dst[3*MATE + off]);
            }
        };
        STAGE(0, kc0);
        int cur = 0;
        for (int kc = kc0; kc < kc1; kc += BKS) {
            if (kc + BKS < kc1) {
                STAGE(cur ^ 1, kc + BKS);
                asm volatile("s_waitcnt vmcnt(8)" ::: "memory");
            } else {
                asm volatile("s_waitcnt vmcnt(0)" ::: "memory");
            }
            __builtin_amdgcn_s_barrier();        // buf[cur] staged for ALL waves
            const us* As_  = smem + cur * BUFE;
            const us* Bs_  = As_ + MATE;
            const us* As2_ = As_ + 2*MATE;
            const us* Bs2_ = As_ + 3*MATE;
            f16x8 a1[4], b1[4], a2[4], b2[4];
            #pragma unroll
            for (int i = 0; i < 4; ++i) {
                a1[i] = *(const f16x8*)&As_ [(mw + i*16 + lr) * BKS + lq*8];
                a2[i] = *(const f16x8*)&As2_[(mw + i*16 + lr) * BKS + lq*8];
            }
            #pragma unroll
            for (int j = 0; j < 4; ++j) {
                b1[j] = *(const f16x8*)&Bs_ [(nw + j*16 + lr) * BKS + lq*8];
                b2[j] = *(const f16x8*)&Bs2_[(nw + j*16 + lr) * BKS + lq*8];
            }
            #pragma unroll
            for (int i = 0; i < 4; ++i)
                #pragma unroll
                for (int j = 0; j < 4; ++j) {
                    acc[i][j] = __builtin_amdgcn_mfma_f32_16x16x32_f16(a2[i], b1[j], acc[i][j], 0, 0, 0);
                    acc[i][j] = __builtin_amdgcn_mfma_f32_16x16x32_f16(a1[i], b2[j], acc[i][j], 0, 0, 0);
                    acc[i][j] = __builtin_amdgcn_mfma_f32_16x16x32_f16(a1[i], b1[j], acc[i][j], 0, 0, 0);
                }
            __builtin_amdgcn_s_barrier();        // buf[cur] free to overwrite
            cur ^= 1;
        }
    } else {
        // ---- plain path: BK=64 dbuf + counted vmcnt (round-7, proven) ----
        constexpr int BUFE = 2*128*64;           // A+B buffer set (32 KB)
        auto STAGE = [&](int b, int kc) {        // exactly 8 loads per thread
            us* dst = smem + b * BUFE;
            #pragma unroll
            for (int i = 0; i < 4; ++i) {
                const int r = crow + i * 32;
                const size_t off = (size_t)(i*256 + tid) * 8;
                gload16(&A1b[(size_t)(m0 + r) * Kv + kc + ccol], &dst[off]);
                gload16(&B1b[(size_t)(n0 + r) * Kv + kc + ccol], &dst[128*64 + off]);
            }
        };
        STAGE(0, kc0);
        int cur = 0;
        for (int kc = kc0; kc < kc1; kc += 64) {
            const bool pf = (kc + 64 < kc1);
            if (pf) {
                STAGE(cur ^ 1, kc + 64);
                asm volatile("s_waitcnt vmcnt(8)" ::: "memory");
            } else {
                asm volatile("s_waitcnt vmcnt(0)" ::: "memory");
            }
            __builtin_amdgcn_s_barrier();        // buf[cur] staged for ALL waves
            const us* As_ = smem + cur * BUFE;
            const us* Bs_ = As_ + 128*64;
            #pragma unroll
            for (int kk = 0; kk < 64; kk += 32) {
                f16x8 a1[4], b1[4];
                #pragma unroll
                for (int i = 0; i < 4; ++i)
                    a1[i] = *(const f16x8*)&As_[(mw + i*16 + lr) * 64 + kk + lq*8];
                #pragma unroll
                for (int j = 0; j < 4; ++j)
                    b1[j] = *(const f16x8*)&Bs_[(nw + j*16 + lr) * 64 + kk + lq*8];
                #pragma unroll
                for (int i = 0; i < 4; ++i)
                    #pragma unroll
                    for (int j = 0; j < 4; ++j)
                        acc[i][j] = __builtin_amdgcn_mfma_f32_16x16x32_f16(a1[i], b1[j], acc[i][j], 0, 0, 0);
            }
            __builtin_amdgcn_s_barrier();        // buf[cur] free to overwrite
            cur ^= 1;
        }
    }

    // ---------------- coalesced epilogue ----------------
    float* slab = (float*)smem + (size_t)w * 2048;   // 32x64 fp32 per-wave slab
    const int lrow0 = lane >> 3, cb = (lane & 7) * 8;
    #pragma unroll
    for (int p = 0; p < 2; ++p) {
        #pragma unroll
        for (int ii = 0; ii < 2; ++ii) {
            const int i = p*2 + ii;
            #pragma unroll
            for (int j = 0; j < 4; ++j)
                #pragma unroll
                for (int r = 0; r < 4; ++r)
                    slab[(ii*16 + lq*4 + r)*64 + j*16 + lr] = acc[i][j][r];
        }
        __syncthreads();
        #pragma unroll
        for (int t = 0; t < 4; ++t) {
            const int lrow = t*8 + lrow0;
            const int grow = m0 + mw + p*32 + lrow;
            const int gcol = n0 + nw + cb;
            const size_t idx = (size_t)grow * Nv + gcol;
            float v[8];
            #pragma unroll
            for (int u = 0; u < 8; ++u) v[u] = slab[lrow*64 + cb + u];
            if (EPI == 0) {
                float* Cf = (float*)Cv + (size_t)blockIdx.z * sC;
                float4 o0 = {v[0],v[1],v[2],v[3]}, o1 = {v[4],v[5],v[6],v[7]};
                *(float4*)&Cf[idx] = o0;
                *(float4*)&Cf[idx+4] = o1;
            } else if (EPI == 1 || EPI == 2) {
                us* Ch = (us*)Cv + (size_t)blockIdx.z * sC;
                us8 o;
                #pragma unroll
                for (int u = 0; u < 8; ++u) {
                    const float tv = v[u] + (bias ? bias[gcol + u] : 0.f);
                    o[u] = f2h(EPI == 2 ? cosf(tv) : tv);
                }
                *(us8*)&Ch[idx] = o;
            } else {                                  // EPI == 4: row bias
                us* Ch = (us*)Cv + (size_t)blockIdx.z * sC;
                const float rb = bias ? bias[grow] : 0.f;
                us8 o;
                #pragma unroll
                for (int u = 0; u < 8; ++u) o[u] = f2h(v[u] + rb);
                *(us8*)&Ch[idx] = o;
            }
        }
        __syncthreads();
    }
}

// ---------------------------------------------------------------------------
// Row softmax: S fp32 [S_] per row -> normalized P fp16. One block per row.
// ---------------------------------------------------------------------------
__global__ __launch_bounds__(256)
void softmax_k(const float* __restrict__ S, us* __restrict__ P) {
    __shared__ float red[8];
    const int tid = threadIdx.x;
    const int lane = tid & 63, w = tid >> 6;
    const float* row = S + (size_t)blockIdx.x * S_;

    const float4 v0 = *(const float4*)&row[tid*8];
    const float4 v1 = *(const float4*)&row[tid*8 + 4];
    float e[8] = {v0.x, v0.y, v0.z, v0.w, v1.x, v1.y, v1.z, v1.w};

    float mx = e[0];
    #pragma unroll
    for (int j = 1; j < 8; ++j) mx = fmaxf(mx, e[j]);
    #pragma unroll
    for (int off = 1; off < 64; off <<= 1) mx = fmaxf(mx, __shfl_xor(mx, off));
    if (lane == 0) red[w] = mx;
    __syncthreads();
    mx = fmaxf(fmaxf(red[0], red[1]), fmaxf(red[2], red[3]));

    float sum = 0.f;
    #pragma unroll
    for (int j = 0; j < 8; ++j) { e[j] = __expf(e[j] - mx); sum += e[j]; }
    #pragma unroll
    for (int off = 1; off < 64; off <<= 1) sum += __shfl_xor(sum, off);
    if (lane == 0) red[4 + w] = sum;
    __syncthreads();
    const float inv = 1.0f / (red[4] + red[5] + red[6] + red[7]);

    us8 o;
    #pragma unroll
    for (int j = 0; j < 8; ++j) o[j] = f2h(e[j] * inv);
    *(us8*)&P[(size_t)blockIdx.x * S_ + tid*8] = o;
}

// ---------------------------------------------------------------------------
extern "C" void kernel_launch(void* const* d_in, const int* in_sizes, int n_in,
                              void* d_out, int out_size, void* d_ws, size_t ws_size,
                              hipStream_t stream) {
    const float* x  = (const float*)d_in[0];
    const float* y  = (const float*)d_in[1];
    const float* Wq = (const float*)d_in[2];
    const float* bq = (const float*)d_in[3];
    const float* Wk = (const float*)d_in[4];
    const float* bk = (const float*)d_in[5];
    const float* Wv = (const float*)d_in[6];
    const float* bv = (const float*)d_in[7];
    const float* Wr = (const float*)d_in[8];
    const float* br = (const float*)d_in[9];
    float* out = (float*)d_out;

    // ALGEBRA: Kh = cos(y@W' + b'), W' = Wk@Wr (K-split x8 + reduce),
    // b' = bk@Wr + br.  Kh itself stays ONE split GEMM (round-5 lesson).
    //
    // Workspace choreography (96 MB) == round-4 (verified passing):
    //  [ 0,16) y1                         live: cast .. V^T gemm
    //  [16,32) y2 -> xh -> P(b0,b1)
    //  [32,48) {Wp lo half} -> Qb -> P(b2,b3)
    //  [48,64) {Wp hi half} -> Kh
    //  [64,96) Wkf1@64 Wkf2@66 Wr1@68 Wr2@70 WT1@72 WT2@74 bp@76
    //          -> Wq1@64 -> S2@64 (32 MB) -> Vt@64 (16 MB), Wv1@80
    //  Wp (8 fp32 slabs, 32 MB) occupies [32,64) only during the W' chain;
    //  dead before Qb and Kh are written.
    // Pair {0,1} scores run FIRST (P01 lands @16 after xh dies); pair {2,3}
    // second (P23 @32 after Qb dies) -> P contiguous 0..3 -> one z=4 PV.
    char* wsb = (char*)d_ws;
    us*    y1   = (us*)(wsb +  0*MBYTE);
    us*    y2   = (us*)(wsb + 16*MBYTE);
    us*    xh   = (us*)(wsb + 16*MBYTE);
    us*    Pb   = (us*)(wsb + 16*MBYTE);    // P batches 0..3 contiguous [16,48)
    float* Wp   = (float*)(wsb + 32*MBYTE); // 8 x 4MB fp32 K-split partials
    us*    Qb   = (us*)(wsb + 32*MBYTE);
    us*    P23  = (us*)(wsb + 32*MBYTE);
    us*    Kh   = (us*)(wsb + 48*MBYTE);
    us*    Wkf1 = (us*)(wsb + 64*MBYTE);
    us*    Wkf2 = (us*)(wsb + 66*MBYTE);
    us*    Wr1  = (us*)(wsb + 68*MBYTE);
    us*    Wr2  = (us*)(wsb + 70*MBYTE);
    us*    WT1  = (us*)(wsb + 72*MBYTE);
    us*    WT2  = (us*)(wsb + 74*MBYTE);
    float* bp   = (float*)(wsb + 76*MBYTE);
    us*    Wq1  = (us*)(wsb + 64*MBYTE);
    float* S2   = (float*)(wsb + 64*MBYTE); // 32 MB, reused per batch pair
    us*    Vt   = (us*)(wsb + 64*MBYTE);    // [b][d][s] 16 MB
    us*    Wv1  = (us*)(wsb + 80*MBYTE);

    const dim3 bb(256);
    const dim3 gcast(M_*D_/1024), gcastW(D_*D_/1024), gw(16,16);
    const dim3 gproj(M_/128, D_/128);            // m on x -> XCD A-panel sharing

    // --- W' = Wk@Wr (K-split x8 + reduce), b' = bk@Wr + br ---
    cast2_k<1><<<gcast, bb, 0, stream>>>(y, y1, y2);
    cast2_k<1><<<gcastW, bb, 0, stream>>>(Wk, Wkf1, Wkf2);   // [d][e] flat
    wsplit_k<1><<<gw, bb, 0, stream>>>(Wr, Wr1, Wr2);        // [r][e]
    bpinit_k<<<dim3(D_/256), bb, 0, stream>>>(br, bp);
    bprime_k<<<dim3(D_/256, 16), bb, 0, stream>>>(bk, Wr, bp);
    gemm_bt_k<D_, D_, 1, 0, 8><<<dim3(D_/128, D_/128, 8), bb, 0, stream>>>(
        Wr1, Wr2, Wkf1, Wkf2, nullptr, (void*)Wp, 0, 0, (long)D_*D_);
    wreduce_k<<<dim3(D_*D_/1024), bb, 0, stream>>>(Wp, WT1, WT2);

    // --- Kh = cos(y@W' + b'): one split GEMM (dbuf BK=32 counted-vmcnt) ---
    gemm_bt_k<D_, D_, 1, 2, 1><<<gproj, bb, 0, stream>>>(
        y1, y2, WT1, WT2, bp, (void*)Kh, 0, 0, 0);

    // --- Q ---
    cast2_k<0><<<gcast, bb, 0, stream>>>(x, xh, nullptr);
    wsplit_k<0><<<gw, bb, 0, stream>>>(Wq, Wq1, nullptr);
    gemm_bt_k<D_, D_, 0, 1, 1><<<gproj, bb, 0, stream>>>(
        xh, nullptr, Wq1, nullptr, bq, (void*)Qb, 0, 0, 0);

    // --- attention scores + softmax, batch pairs (z=2 -> 512 blocks, 2/CU).
    //     Pair {0,1} first (see layout). ---
    gemm_bt_k<S_, D_, 0, 0, 1><<<dim3(S_/128, S_/128, 2), bb, 0, stream>>>(
        Qb, nullptr, Kh, nullptr, nullptr,
        (void*)S2, (long)S_*D_, (long)S_*D_, (long)S_*S_);
    softmax_k<<<dim3(2*S_), bb, 0, stream>>>(S2, Pb);
    gemm_bt_k<S_, D_, 0, 0, 1><<<dim3(S_/128, S_/128, 2), bb, 0, stream>>>(
        Qb + 2*(size_t)S_*D_, nullptr, Kh + 2*(size_t)S_*D_, nullptr, nullptr,
        (void*)S2, (long)S_*D_, (long)S_*D_, (long)S_*S_);
    softmax_k<<<dim3(2*S_), bb, 0, stream>>>(S2, P23);

    // --- V^T directly: Vt[b][d][s] = sum_e Wv^T[d][e]*y[b][s][e] + bv[d] ---
    wsplit_k<0><<<gw, bb, 0, stream>>>(Wv, Wv1, nullptr);
    gemm_bt_k<S_, D_, 0, 4, 1><<<dim3(D_/128, S_/128, B_), bb, 0, stream>>>(
        Wv1, nullptr, y1, nullptr, bv, (void*)Vt,
        0, (long)S_*D_, (long)D_*S_);

    // --- PV: single z=4 dispatch, P contiguous in batch order ---
    gemm_bt_k<D_, S_, 0, 0, 1><<<dim3(S_/128, D_/128, B_), bb, 0, stream>>>(
        Pb, nullptr, Vt, nullptr, nullptr, (void*)out,
        (long)S_*S_, (long)D_*S_, (long)S_*D_);
}

// Round 9
// 394.949 us; speedup vs baseline: 1.3424x; 1.0765x over previous
//
#include <hip/hip_runtime.h>
#include <hip/hip_bf16.h>
#include <math.h>

#define B_ 4
#define S_ 2048
#define D_ 1024
#define M_ (B_*S_)   // 8192 rows total across batch
#define MBYTE (1024ull*1024ull)

typedef __attribute__((ext_vector_type(8))) _Float16 f16x8;  // 8 f16 = 4 VGPRs (MFMA A/B frag)
typedef __attribute__((ext_vector_type(4))) float f32x4;     // MFMA C/D frag
typedef __attribute__((ext_vector_type(8))) unsigned short us8;
typedef unsigned short us;

__device__ inline us f2h(float f) {
    union { _Float16 h; us u; } x;
    x.h = (_Float16)f;   // RTE
    return x.u;
}
__device__ inline float h2f(us u) {
    union { us u; _Float16 h; } x; x.u = u;
    return (float)x.h;
}

__device__ inline void gload16(const us* g, us* l) {
    __builtin_amdgcn_global_load_lds(
        (const __attribute__((address_space(1))) unsigned int*)g,
        (__attribute__((address_space(3))) unsigned int*)l, 16, 0, 0);
}

// ---------------------------------------------------------------------------
// Split cast: f32 -> hi fp16 (+ lo fp16 residual if DO_LO). 4 elems/thread.
// ---------------------------------------------------------------------------
template<int DO_LO>
__global__ __launch_bounds__(256)
void cast2_k(const float* __restrict__ in, us* __restrict__ hi, us* __restrict__ lo) {
    const size_t i = ((size_t)blockIdx.x * 256 + threadIdx.x) * 4;
    const float4 v = *(const float4*)&in[i];
    ushort4 h;
    h.x = f2h(v.x); h.y = f2h(v.y); h.z = f2h(v.z); h.w = f2h(v.w);
    *(ushort4*)&hi[i] = h;
    if (DO_LO) {
        ushort4 l;
        l.x = f2h(v.x - h2f(h.x)); l.y = f2h(v.y - h2f(h.y));
        l.z = f2h(v.z - h2f(h.z)); l.w = f2h(v.w - h2f(h.w));
        *(ushort4*)&lo[i] = l;
    }
}

// ---------------------------------------------------------------------------
// Weight transpose + split cast: W fp32 [K][N] -> Wt1(,Wt2) fp16 [N][K].
// ---------------------------------------------------------------------------
template<int DO_LO>
__global__ __launch_bounds__(256)
void wsplit_k(const float* __restrict__ W, us* __restrict__ Wt1, us* __restrict__ Wt2) {
    __shared__ float t[64][65];
    const int tid = threadIdx.x;
    const int k0 = blockIdx.x*64, n0 = blockIdx.y*64;
    #pragma unroll
    for (int i = 0; i < 4; ++i) {
        const int c = i*256 + tid;
        const int row = c >> 4, col = (c & 15) * 4;
        const float4 v = *(const float4*)&W[(size_t)(k0+row)*D_ + n0+col];
        t[row][col]=v.x; t[row][col+1]=v.y; t[row][col+2]=v.z; t[row][col+3]=v.w;
    }
    __syncthreads();
    #pragma unroll
    for (int i = 0; i < 4; ++i) {
        const int c = i*256 + tid;
        const int n = c >> 4, k = (c & 15) * 4;
        float f[4] = { t[k][n], t[k+1][n], t[k+2][n], t[k+3][n] };
        ushort4 h;
        h.x=f2h(f[0]); h.y=f2h(f[1]); h.z=f2h(f[2]); h.w=f2h(f[3]);
        *(ushort4*)&Wt1[(size_t)(n0+n)*D_ + k0+k] = h;
        if (DO_LO) {
            ushort4 l;
            l.x=f2h(f[0]-h2f(h.x)); l.y=f2h(f[1]-h2f(h.y));
            l.z=f2h(f[2]-h2f(h.z)); l.w=f2h(f[3]-h2f(h.w));
            *(ushort4*)&Wt2[(size_t)(n0+n)*D_ + k0+k] = l;
        }
    }
}

// ---------------------------------------------------------------------------
// Reduce 8 fp32 K-split partial slabs of W' and emit hi/lo split fp16.
// ---------------------------------------------------------------------------
__global__ __launch_bounds__(256)
void wreduce_k(const float* __restrict__ Wp, us* __restrict__ W1, us* __restrict__ W2) {
    const size_t i = ((size_t)blockIdx.x * 256 + threadIdx.x) * 4;
    float4 s = *(const float4*)&Wp[i];
    #pragma unroll
    for (int z = 1; z < 8; ++z) {
        const float4 v = *(const float4*)&Wp[(size_t)z*D_*D_ + i];
        s.x += v.x; s.y += v.y; s.z += v.z; s.w += v.w;
    }
    ushort4 h, l;
    h.x=f2h(s.x); h.y=f2h(s.y); h.z=f2h(s.z); h.w=f2h(s.w);
    l.x=f2h(s.x-h2f(h.x)); l.y=f2h(s.y-h2f(h.y));
    l.z=f2h(s.z-h2f(h.z)); l.w=f2h(s.w-h2f(h.w));
    *(ushort4*)&W1[i] = h;
    *(ushort4*)&W2[i] = l;
}

// ---------------------------------------------------------------------------
// b' = bk @ Wr + br. ROUND-3 LESSON: 4-block version was latency-bound.
// bpinit seeds bp=br; bprime does (4,16) e-chunked partials via atomicAdd.
// ---------------------------------------------------------------------------
__global__ __launch_bounds__(256)
void bpinit_k(const float* __restrict__ br, float* __restrict__ bp) {
    const int r = blockIdx.x * 256 + threadIdx.x;
    bp[r] = br[r];
}
__global__ __launch_bounds__(256)
void bprime_k(const float* __restrict__ bk, const float* __restrict__ Wr,
              float* __restrict__ bp) {
    const int r = blockIdx.x * 256 + threadIdx.x;
    const int e0 = blockIdx.y * 64;
    float a0 = 0.f, a1 = 0.f, a2 = 0.f, a3 = 0.f;
    for (int e = e0; e < e0 + 64; e += 4) {
        a0 += bk[e+0] * Wr[(size_t)(e+0)*D_ + r];
        a1 += bk[e+1] * Wr[(size_t)(e+1)*D_ + r];
        a2 += bk[e+2] * Wr[(size_t)(e+2)*D_ + r];
        a3 += bk[e+3] * Wr[(size_t)(e+3)*D_ + r];
    }
    atomicAdd(&bp[r], (a0 + a1) + (a2 + a3));
}

// ---------------------------------------------------------------------------
// fp16 MFMA GEMM: C[M][N] = A[M][K] @ Bt[N][K]^T, fp32 accumulate.
// 128x128 tile, 4 waves 2x2, global_load_lds width-16 staging.
// blockIdx.x = M-tile (XCD = blk%8 = m%8 -> A-panel L2 sharing on one XCD).
//
// Pipeline (T3+T4, rounds 7-8, proven): dbuf + COUNTED vmcnt across RAW
// barriers: {STAGE(next)=8 loads; vmcnt(8); s_barrier; COMPUTE(cur);
// s_barrier}. SPLIT=0: BK=64. SPLIT=1: BK=32, 4 matrices.
//
// ROUND-9: T2 XOR-swizzle (rule #21: both-sides-or-neither with
// global_load_lds -- linear LDS dest, PERMUTED per-lane GLOBAL source col,
// matching XOR on the ds_read address).
//   Why: fragment reads were bank-broken. BK=64 row stride = 128 B == bank
//   0 mod 32 -> all 16 lr-lanes of an lq group hit one bank-quad = 16-way
//   conflict (5.7x, m136) on every ds_read_b128; BK=32 (64 B stride) =
//   8-way. Measured SQ_LDS_BANK_CONFLICT 1.3e7 (BK=64) / 4.6e6 (Kh) ~= 27%
//   of hot-dispatch cycles. Counted-vmcnt (r7/8) amortized the stage stall,
//   moving LDS reads onto the critical path (m252 regime mechanism).
//   Swizzle: BK=64 LDS[r][c] = G[r][c^(r&7)], read cg = ((kk>>3)+lq)^(lr&7)
//            BK=32 LDS[r][c] = G[r][c^((r>>1)&3)], read cg = lq^((lr>>1)&3)
//   Both give 8 distinct bank-quads per 8 lanes -> 2-way = free. Source
//   permutation stays within one 128B/64B line -> coalescing preserved.
//   Pure layout permutation: identical arithmetic, absmax unchanged.
//
// ROUND-1 LESSON: don't lower MFMA-per-staged-byte (127->264us).
// ROUND-3 LESSON: <256-block dispatches are latency-dead; K-split (KS).
// ROUND-5 LESSON: don't split the split-GEMM into plain passes (+63% bytes).
// ROUND-6 LESSON: dbuf under __syncthreads is useless (implicit vmcnt(0));
//   only counted-vmcnt pays (confirmed r7 plain, r8 split).
//
// EPI: 0 = fp32 store (z-offset sC); 1 = f16(acc + colbias);
//      2 = f16(cos(acc + colbias)); 4 = f16(acc + ROW bias) [direct-V^T].
// Epilogue is LDS-staged so all global stores are 16B/lane coalesced.
// ---------------------------------------------------------------------------
template<int Nv, int Kv, int SPLIT, int EPI, int KS>
__global__ __launch_bounds__(256)
void gemm_bt_k(const us* __restrict__ A1, const us* __restrict__ A2,
               const us* __restrict__ B1, const us* __restrict__ B2,
               const float* __restrict__ bias, void* __restrict__ Cv,
               long sA, long sB, long sC) {
    __shared__ us smem[4*128*64];                // 64 KB both modes
    const int tid = threadIdx.x;
    const us* A1b = A1 + (size_t)blockIdx.z * sA;
    const us* A2b = SPLIT ? A2 + (size_t)blockIdx.z * sA : nullptr;
    const us* B1b = B1 + (size_t)blockIdx.z * sB;
    const us* B2b = SPLIT ? B2 + (size_t)blockIdx.z * sB : nullptr;
    const int m0 = blockIdx.x * 128, n0 = blockIdx.y * 128;   // m on x: XCD swizzle
    const int lane = tid & 63, w = tid >> 6;
    const int mw = (w >> 1) * 64, nw = (w & 1) * 64;
    const int lr = lane & 15, lq = lane >> 4;

    f32x4 acc[4][4];
    #pragma unroll
    for (int i = 0; i < 4; ++i)
        #pragma unroll
        for (int j = 0; j < 4; ++j)
            acc[i][j] = (f32x4){0.f, 0.f, 0.f, 0.f};

    int kc0 = 0, kc1 = Kv;
    if (KS > 1) {
        const int kchunk = Kv / KS;
        kc0 = blockIdx.z * kchunk;
        kc1 = kc0 + kchunk;
    }

    if constexpr (SPLIT) {
        // ---- split path: BK=32 dbuf + counted vmcnt + swizzle ----
        constexpr int BKS  = 32;
        constexpr int MATE = 128 * BKS;          // elems per matrix (8 KB)
        constexpr int BUFE = 4 * MATE;           // buffer set (32 KB)
        const int r0 = tid >> 2;                 // staging row (0..63, +64/i)
        // swizzled global source col-group: c ^ ((row>>1)&3); row>>1 of the
        // staged row == tid>>3 (i*64 contributes 0 mod 8) -> thread-const.
        const int sc = (((tid & 3) ^ ((tid >> 3) & 3))) * 8;
        auto STAGE = [&](int b, int kc) {        // exactly 8 loads per thread
            us* dst = smem + b * BUFE;
            #pragma unroll
            for (int i = 0; i < 2; ++i) {
                const int r = r0 + i * 64;
                const size_t off = (size_t)(i*256 + tid) * 8;   // linear row*BKS+col
                gload16(&A1b[(size_t)(m0 + r) * Kv + kc + sc], &dst[off]);
                gload16(&B1b[(size_t)(n0 + r) * Kv + kc + sc], &dst[MATE + off]);
                gload16(&A2b[(size_t)(m0 + r) * Kv + kc + sc], &dst[2*MATE + off]);
                gload16(&B2b[(size_t)(n0 + r) * Kv + kc + sc], &dst[3*MATE + off]);
            }
        };
        const int cg = (lq ^ ((lr >> 1) & 3)) * 8;   // swizzled read col
        STAGE(0, kc0);
        int cur = 0;
        for (int kc = kc0; kc < kc1; kc += BKS) {
            if (kc + BKS < kc1) {
                STAGE(cur ^ 1, kc + BKS);
                asm volatile("s_waitcnt vmcnt(8)" ::: "memory");
            } else {
                asm volatile("s_waitcnt vmcnt(0)" ::: "memory");
            }
            __builtin_amdgcn_s_barrier();        // buf[cur] staged for ALL waves
            const us* As_  = smem + cur * BUFE;
            const us* Bs_  = As_ + MATE;
            const us* As2_ = As_ + 2*MATE;
            const us* Bs2_ = As_ + 3*MATE;
            f16x8 a1[4], b1[4], a2[4], b2[4];
            #pragma unroll
            for (int i = 0; i < 4; ++i) {
                a1[i] = *(const f16x8*)&As_ [(mw + i*16 + lr) * BKS + cg];
                a2[i] = *(const f16x8*)&As2_[(mw + i*16 + lr) * BKS + cg];
            }
            #pragma unroll
            for (int j = 0; j < 4; ++j) {
                b1[j] = *(const f16x8*)&Bs_ [(nw + j*16 + lr) * BKS + cg];
                b2[j] = *(const f16x8*)&Bs2_[(nw + j*16 + lr) * BKS + cg];
            }
            #pragma unroll
            for (int i = 0; i < 4; ++i)
                #pragma unroll
                for (int j = 0; j < 4; ++j) {
                    acc[i][j] = __builtin_amdgcn_mfma_f32_16x16x32_f16(a2[i], b1[j], acc[i][j], 0, 0, 0);
                    acc[i][j] = __builtin_amdgcn_mfma_f32_16x16x32_f16(a1[i], b2[j], acc[i][j], 0, 0, 0);
                    acc[i][j] = __builtin_amdgcn_mfma_f32_16x16x32_f16(a1[i], b1[j], acc[i][j], 0, 0, 0);
                }
            __builtin_amdgcn_s_barrier();        // buf[cur] free to overwrite
            cur ^= 1;
        }
    } else {
        // ---- plain path: BK=64 dbuf + counted vmcnt + swizzle ----
        constexpr int BUFE = 2*128*64;           // A+B buffer set (32 KB)
        const int crow = tid >> 3;               // staging row (0..31, +32/i)
        // swizzled global source col-group: c ^ (row&7); row&7 == (tid>>3)&7
        // for every i (i*32 == 0 mod 8) -> thread-const.
        const int sc = ((tid & 7) ^ ((tid >> 3) & 7)) * 8;
        auto STAGE = [&](int b, int kc) {        // exactly 8 loads per thread
            us* dst = smem + b * BUFE;
            #pragma unroll
            for (int i = 0; i < 4; ++i) {
                const int r = crow + i * 32;
                const size_t off = (size_t)(i*256 + tid) * 8;   // linear row*64+col
                gload16(&A1b[(size_t)(m0 + r) * Kv + kc + sc], &dst[off]);
                gload16(&B1b[(size_t)(n0 + r) * Kv + kc + sc], &dst[128*64 + off]);
            }
        };
        STAGE(0, kc0);
        int cur = 0;
        for (int kc = kc0; kc < kc1; kc += 64) {
            const bool pf = (kc + 64 < kc1);
            if (pf) {
                STAGE(cur ^ 1, kc + 64);
                asm volatile("s_waitcnt vmcnt(8)" ::: "memory");
            } else {
                asm volatile("s_waitcnt vmcnt(0)" ::: "memory");
            }
            __builtin_amdgcn_s_barrier();        // buf[cur] staged for ALL waves
            const us* As_ = smem + cur * BUFE;
            const us* Bs_ = As_ + 128*64;
            #pragma unroll
            for (int kk = 0; kk < 64; kk += 32) {
                f16x8 a1[4], b1[4];
                #pragma unroll
                for (int i = 0; i < 4; ++i) {
                    const int cg = ((((kk >> 3) + lq) ^ (lr & 7))) * 8;
                    a1[i] = *(const f16x8*)&As_[(mw + i*16 + lr) * 64 + cg];
                }
                #pragma unroll
                for (int j = 0; j < 4; ++j) {
                    const int cg = ((((kk >> 3) + lq) ^ (lr & 7))) * 8;
                    b1[j] = *(const f16x8*)&Bs_[(nw + j*16 + lr) * 64 + cg];
                }
                #pragma unroll
                for (int i = 0; i < 4; ++i)
                    #pragma unroll
                    for (int j = 0; j < 4; ++j)
                        acc[i][j] = __builtin_amdgcn_mfma_f32_16x16x32_f16(a1[i], b1[j], acc[i][j], 0, 0, 0);
            }
            __builtin_amdgcn_s_barrier();        // buf[cur] free to overwrite
            cur ^= 1;
        }
    }

    // ---------------- coalesced epilogue ----------------
    float* slab = (float*)smem + (size_t)w * 2048;   // 32x64 fp32 per-wave slab
    const int lrow0 = lane >> 3, cb = (lane & 7) * 8;
    #pragma unroll
    for (int p = 0; p < 2; ++p) {
        #pragma unroll
        for (int ii = 0; ii < 2; ++ii) {
            const int i = p*2 + ii;
            #pragma unroll
            for (int j = 0; j < 4; ++j)
                #pragma unroll
                for (int r = 0; r < 4; ++r)
                    slab[(ii*16 + lq*4 + r)*64 + j*16 + lr] = acc[i][j][r];
        }
        __syncthreads();
        #pragma unroll
        for (int t = 0; t < 4; ++t) {
            const int lrow = t*8 + lrow0;
            const int grow = m0 + mw + p*32 + lrow;
            const int gcol = n0 + nw + cb;
            const size_t idx = (size_t)grow * Nv + gcol;
            float v[8];
            #pragma unroll
            for (int u = 0; u < 8; ++u) v[u] = slab[lrow*64 + cb + u];
            if (EPI == 0) {
                float* Cf = (float*)Cv + (size_t)blockIdx.z * sC;
                float4 o0 = {v[0],v[1],v[2],v[3]}, o1 = {v[4],v[5],v[6],v[7]};
                *(float4*)&Cf[idx] = o0;
                *(float4*)&Cf[idx+4] = o1;
            } else if (EPI == 1 || EPI == 2) {
                us* Ch = (us*)Cv + (size_t)blockIdx.z * sC;
                us8 o;
                #pragma unroll
                for (int u = 0; u < 8; ++u) {
                    const float tv = v[u] + (bias ? bias[gcol + u] : 0.f);
                    o[u] = f2h(EPI == 2 ? cosf(tv) : tv);
                }
                *(us8*)&Ch[idx] = o;
            } else {                                  // EPI == 4: row bias
                us* Ch = (us*)Cv + (size_t)blockIdx.z * sC;
                const float rb = bias ? bias[grow] : 0.f;
                us8 o;
                #pragma unroll
                for (int u = 0; u < 8; ++u) o[u] = f2h(v[u] + rb);
                *(us8*)&Ch[idx] = o;
            }
        }
        __syncthreads();
    }
}

// ---------------------------------------------------------------------------
// Row softmax: S fp32 [S_] per row -> normalized P fp16. One block per row.
// ---------------------------------------------------------------------------
__global__ __launch_bounds__(256)
void softmax_k(const float* __restrict__ S, us* __restrict__ P) {
    __shared__ float red[8];
    const int tid = threadIdx.x;
    const int lane = tid & 63, w = tid >> 6;
    const float* row = S + (size_t)blockIdx.x * S_;

    const float4 v0 = *(const float4*)&row[tid*8];
    const float4 v1 = *(const float4*)&row[tid*8 + 4];
    float e[8] = {v0.x, v0.y, v0.z, v0.w, v1.x, v1.y, v1.z, v1.w};

    float mx = e[0];
    #pragma unroll
    for (int j = 1; j < 8; ++j) mx = fmaxf(mx, e[j]);
    #pragma unroll
    for (int off = 1; off < 64; off <<= 1) mx = fmaxf(mx, __shfl_xor(mx, off));
    if (lane == 0) red[w] = mx;
    __syncthreads();
    mx = fmaxf(fmaxf(red[0], red[1]), fmaxf(red[2], red[3]));

    float sum = 0.f;
    #pragma unroll
    for (int j = 0; j < 8; ++j) { e[j] = __expf(e[j] - mx); sum += e[j]; }
    #pragma unroll
    for (int off = 1; off < 64; off <<= 1) sum += __shfl_xor(sum, off);
    if (lane == 0) red[4 + w] = sum;
    __syncthreads();
    const float inv = 1.0f / (red[4] + red[5] + red[6] + red[7]);

    us8 o;
    #pragma unroll
    for (int j = 0; j < 8; ++j) o[j] = f2h(e[j] * inv);
    *(us8*)&P[(size_t)blockIdx.x * S_ + tid*8] = o;
}

// ---------------------------------------------------------------------------
extern "C" void kernel_launch(void* const* d_in, const int* in_sizes, int n_in,
                              void* d_out, int out_size, void* d_ws, size_t ws_size,
                              hipStream_t stream) {
    const float* x  = (const float*)d_in[0];
    const float* y  = (const float*)d_in[1];
    const float* Wq = (const float*)d_in[2];
    const float* bq = (const float*)d_in[3];
    const float* Wk = (const float*)d_in[4];
    const float* bk = (const float*)d_in[5];
    const float* Wv = (const float*)d_in[6];
    const float* bv = (const float*)d_in[7];
    const float* Wr = (const float*)d_in[8];
    const float* br = (const float*)d_in[9];
    float* out = (float*)d_out;

    // ALGEBRA: Kh = cos(y@W' + b'), W' = Wk@Wr (K-split x8 + reduce),
    // b' = bk@Wr + br.  Kh itself stays ONE split GEMM (round-5 lesson).
    //
    // Workspace choreography (96 MB) == round-4 (verified passing):
    //  [ 0,16) y1                         live: cast .. V^T gemm
    //  [16,32) y2 -> xh -> P(b0,b1)
    //  [32,48) {Wp lo half} -> Qb -> P(b2,b3)
    //  [48,64) {Wp hi half} -> Kh
    //  [64,96) Wkf1@64 Wkf2@66 Wr1@68 Wr2@70 WT1@72 WT2@74 bp@76
    //          -> Wq1@64 -> S2@64 (32 MB) -> Vt@64 (16 MB), Wv1@80
    //  Wp (8 fp32 slabs, 32 MB) occupies [32,64) only during the W' chain;
    //  dead before Qb and Kh are written.
    // Pair {0,1} scores run FIRST (P01 lands @16 after xh dies); pair {2,3}
    // second (P23 @32 after Qb dies) -> P contiguous 0..3 -> one z=4 PV.
    char* wsb = (char*)d_ws;
    us*    y1   = (us*)(wsb +  0*MBYTE);
    us*    y2   = (us*)(wsb + 16*MBYTE);
    us*    xh   = (us*)(wsb + 16*MBYTE);
    us*    Pb   = (us*)(wsb + 16*MBYTE);    // P batches 0..3 contiguous [16,48)
    float* Wp   = (float*)(wsb + 32*MBYTE); // 8 x 4MB fp32 K-split partials
    us*    Qb   = (us*)(wsb + 32*MBYTE);
    us*    P23  = (us*)(wsb + 32*MBYTE);
    us*    Kh   = (us*)(wsb + 48*MBYTE);
    us*    Wkf1 = (us*)(wsb + 64*MBYTE);
    us*    Wkf2 = (us*)(wsb + 66*MBYTE);
    us*    Wr1  = (us*)(wsb + 68*MBYTE);
    us*    Wr2  = (us*)(wsb + 70*MBYTE);
    us*    WT1  = (us*)(wsb + 72*MBYTE);
    us*    WT2  = (us*)(wsb + 74*MBYTE);
    float* bp   = (float*)(wsb + 76*MBYTE);
    us*    Wq1  = (us*)(wsb + 64*MBYTE);
    float* S2   = (float*)(wsb + 64*MBYTE); // 32 MB, reused per batch pair
    us*    Vt   = (us*)(wsb + 64*MBYTE);    // [b][d][s] 16 MB
    us*    Wv1  = (us*)(wsb + 80*MBYTE);

    const dim3 bb(256);
    const dim3 gcast(M_*D_/1024), gcastW(D_*D_/1024), gw(16,16);
    const dim3 gproj(M_/128, D_/128);            // m on x -> XCD A-panel sharing

    // --- W' = Wk@Wr (K-split x8 + reduce), b' = bk@Wr + br ---
    cast2_k<1><<<gcast, bb, 0, stream>>>(y, y1, y2);
    cast2_k<1><<<gcastW, bb, 0, stream>>>(Wk, Wkf1, Wkf2);   // [d][e] flat
    wsplit_k<1><<<gw, bb, 0, stream>>>(Wr, Wr1, Wr2);        // [r][e]
    bpinit_k<<<dim3(D_/256), bb, 0, stream>>>(br, bp);
    bprime_k<<<dim3(D_/256, 16), bb, 0, stream>>>(bk, Wr, bp);
    gemm_bt_k<D_, D_, 1, 0, 8><<<dim3(D_/128, D_/128, 8), bb, 0, stream>>>(
        Wr1, Wr2, Wkf1, Wkf2, nullptr, (void*)Wp, 0, 0, (long)D_*D_);
    wreduce_k<<<dim3(D_*D_/1024), bb, 0, stream>>>(Wp, WT1, WT2);

    // --- Kh = cos(y@W' + b'): one split GEMM (dbuf BK=32 counted-vmcnt) ---
    gemm_bt_k<D_, D_, 1, 2, 1><<<gproj, bb, 0, stream>>>(
        y1, y2, WT1, WT2, bp, (void*)Kh, 0, 0, 0);

    // --- Q ---
    cast2_k<0><<<gcast, bb, 0, stream>>>(x, xh, nullptr);
    wsplit_k<0><<<gw, bb, 0, stream>>>(Wq, Wq1, nullptr);
    gemm_bt_k<D_, D_, 0, 1, 1><<<gproj, bb, 0, stream>>>(
        xh, nullptr, Wq1, nullptr, bq, (void*)Qb, 0, 0, 0);

    // --- attention scores + softmax, batch pairs (z=2 -> 512 blocks, 2/CU).
    //     Pair {0,1} first (see layout). ---
    gemm_bt_k<S_, D_, 0, 0, 1><<<dim3(S_/128, S_/128, 2), bb, 0, stream>>>(
        Qb, nullptr, Kh, nullptr, nullptr,
        (void*)S2, (long)S_*D_, (long)S_*D_, (long)S_*S_);
    softmax_k<<<dim3(2*S_), bb, 0, stream>>>(S2, Pb);
    gemm_bt_k<S_, D_, 0, 0, 1><<<dim3(S_/128, S_/128, 2), bb, 0, stream>>>(
        Qb + 2*(size_t)S_*D_, nullptr, Kh + 2*(size_t)S_*D_, nullptr, nullptr,
        (void*)S2, (long)S_*D_, (long)S_*D_, (long)S_*S_);
    softmax_k<<<dim3(2*S_), bb, 0, stream>>>(S2, P23);

    // --- V^T directly: Vt[b][d][s] = sum_e Wv^T[d][e]*y[b][s][e] + bv[d] ---
    wsplit_k<0><<<gw, bb, 0, stream>>>(Wv, Wv1, nullptr);
    gemm_bt_k<S_, D_, 0, 4, 1><<<dim3(D_/128, S_/128, B_), bb, 0, stream>>>(
        Wv1, nullptr, y1, nullptr, bv, (void*)Vt,
        0, (long)S_*D_, (long)D_*S_);

    // --- PV: single z=4 dispatch, P contiguous in batch order ---
    gemm_bt_k<D_, S_, 0, 0, 1><<<dim3(S_/128, D_/128, B_), bb, 0, stream>>>(
        Pb, nullptr, Vt, nullptr, nullptr, (void*)out,
        (long)S_*S_, (long)D_*S_, (long)S_*D_);
}